// Round 1
// baseline (2389.637 us; speedup 1.0000x reference)
//
#include <hip/hip_runtime.h>
#include <cstdint>

#define DI __device__ __forceinline__

typedef __attribute__((ext_vector_type(8))) short bx8;   // 8 x bf16 (bit pattern)
typedef __attribute__((ext_vector_type(4))) float f4;
typedef unsigned short u16;
typedef unsigned int u32;

// ---------------- problem constants ----------------
constexpr int NB = 1024;         // batch
constexpr int NN = 196;          // tokens
constexpr int NC = 384;          // channels
constexpr int NH = 12;           // heads
constexpr int HD = 32;           // head dim
constexpr int MM = NB * NN;      // 200704 rows
constexpr int C3 = 3 * NC;       // 1152
constexpr int PH = NN * HD;      // 6272 elements per (b,h)

// workspace layout (bytes)
constexpr size_t SZ_T    = (size_t)NB * NH * PH * 4;   // 308,281,344 per tensor
constexpr size_t OFF_Q   = 0;
constexpr size_t OFF_K   = SZ_T;
constexpr size_t OFF_V   = 2 * SZ_T;                   // v, later reused as y
constexpr size_t OFF_WQH = 3 * SZ_T;
constexpr size_t SZ_WQ   = (size_t)C3 * NC * 2;        // 884,736
constexpr size_t OFF_WQL = OFF_WQH + SZ_WQ;
constexpr size_t OFF_WPH = OFF_WQL + SZ_WQ;
constexpr size_t SZ_WP   = (size_t)NC * NC * 2;        // 294,912
constexpr size_t OFF_WPL = OFF_WPH + SZ_WP;
// total required: 927,203,328 bytes

DI void gload_lds16(const void* g, void* l) {
  using GP = const void __attribute__((address_space(1)))*;
  using LP = void __attribute__((address_space(3)))*;
  __builtin_amdgcn_global_load_lds((GP)g, (LP)l, 16, 0, 0);
}

// split fp32 into bf16 hi (bit-truncate) + bf16 lo (truncated residual)
DI void split_hi_lo(float f, short& hi, short& lo) {
  u32 u = __float_as_uint(f);
  hi = (short)(u >> 16);
  float l = f - __uint_as_float(u & 0xffff0000u);   // exact (Sterbenz)
  lo = (short)(__float_as_uint(l) >> 16);
}

// ---------------- kernel 0: pre-split weight matrices ----------------
__global__ void split_weights(const float* __restrict__ qw, const float* __restrict__ pw,
                              u16* __restrict__ qh, u16* __restrict__ ql,
                              u16* __restrict__ ph, u16* __restrict__ pl)
{
  int i = blockIdx.x * 256 + threadIdx.x;
  if (i < C3 * NC) {
    float f = qw[i];
    u32 u = __float_as_uint(f);
    qh[i] = (u16)(u >> 16);
    float lo = f - __uint_as_float(u & 0xffff0000u);
    u32 ul = __float_as_uint(lo);
    ul += 0x7fffu + ((ul >> 16) & 1u);               // RNE on residual
    ql[i] = (u16)(ul >> 16);
  }
  if (i < NC * NC) {
    float f = pw[i];
    u32 u = __float_as_uint(f);
    ph[i] = (u16)(u >> 16);
    float lo = f - __uint_as_float(u & 0xffff0000u);
    u32 ul = __float_as_uint(lo);
    ul += 0x7fffu + ((ul >> 16) & 1u);
    pl[i] = (u16)(ul >> 16);
  }
}

// ---------------- kernel 1: qkv = x @ qkv_w^T + b ; relu/pos ; head-split ----------------
// 128x128 tile, BK=32, 4 waves (2x2 of 64x64). A: fp32 in LDS (XOR-granule swizzle,
// pre-swizzled global src for global_load_lds), split hi/lo in regs. B: pre-split bf16,
// k-major granule layout [kb][t][8].
__global__ __launch_bounds__(256, 2) void qkv_gemm(
    const float* __restrict__ x, const u16* __restrict__ wh, const u16* __restrict__ wl,
    const float* __restrict__ bias, const float* __restrict__ pos,
    float* __restrict__ qo, float* __restrict__ ko, float* __restrict__ vo)
{
  __shared__ __align__(16) char lds[2][32768];   // A fp32 16K | Bh 8K | Bl 8K
  const int tid  = threadIdx.x;
  const int lane = tid & 63, wv = tid >> 6;
  const int L  = ((int)blockIdx.x & 7) * 1764 + ((int)blockIdx.x >> 3); // XCD swizzle (14112=8*1764)
  const int rt = L / 9, ct = L - rt * 9;
  const int m0 = rt * 128, t0 = ct * 128;

  // staging source addresses
  const float* a_src[4];
  {
    int sg = lane & 7, lr = lane >> 3;
#pragma unroll
    for (int j = 0; j < 4; ++j) {
      int r = (wv * 4 + j) * 8 + lr;
      int g = sg ^ (r & 7);                     // pre-swizzled source granule
      a_src[j] = x + (size_t)(m0 + r) * NC + g * 4;
    }
  }
  const u16 *bh_src[2], *bl_src[2];
#pragma unroll
  for (int j = 0; j < 2; ++j) {
    int gi = (wv * 2 + j) * 64 + lane;
    int kb = gi >> 7, t = gi & 127;
    size_t o = (size_t)(t0 + t) * NC + kb * 8;
    bh_src[j] = wh + o;
    bl_src[j] = wl + o;
  }

  auto stage = [&](char* buf, int k0) {
#pragma unroll
    for (int j = 0; j < 4; ++j)
      gload_lds16(a_src[j] + k0, buf + (wv * 4 + j) * 1024);
#pragma unroll
    for (int j = 0; j < 2; ++j) {
      gload_lds16(bh_src[j] + k0, buf + 16384 + (wv * 2 + j) * 1024);
      gload_lds16(bl_src[j] + k0, buf + 24576 + (wv * 2 + j) * 1024);
    }
  };

  const int wm = (wv & 1) * 64, wn = (wv >> 1) * 64;
  const int l15 = lane & 15, l4 = lane >> 4;
  int boff[4], aoff0[4], aoff1[4];
#pragma unroll
  for (int i = 0; i < 4; ++i) {
    boff[i] = (l4 * 128 + wn + i * 16 + l15) * 16;
    int r = wm + i * 16 + l15;
    aoff0[i] = r * 128 + (((l4 * 2)     ^ (r & 7)) * 16);
    aoff1[i] = r * 128 + (((l4 * 2 + 1) ^ (r & 7)) * 16);
  }

  f4 acc[4][4];
  const f4 fz = {0.f, 0.f, 0.f, 0.f};
#pragma unroll
  for (int i = 0; i < 4; ++i)
#pragma unroll
    for (int j = 0; j < 4; ++j) acc[i][j] = fz;

  stage(lds[0], 0);
  for (int kt = 0; kt < 12; ++kt) {
    __syncthreads();
    if (kt < 11) stage(lds[(kt + 1) & 1], (kt + 1) * 32);
    char* buf = lds[kt & 1];
    bx8 bhf[4], blf[4];
#pragma unroll
    for (int i = 0; i < 4; ++i) {
      bhf[i] = *(const bx8*)(buf + 16384 + boff[i]);
      blf[i] = *(const bx8*)(buf + 24576 + boff[i]);
    }
#pragma unroll
    for (int mi = 0; mi < 4; ++mi) {
      f4 fa = *(const f4*)(buf + aoff0[mi]);
      f4 fb = *(const f4*)(buf + aoff1[mi]);
      bx8 ah, al;
#pragma unroll
      for (int e = 0; e < 4; ++e) { short h, l; split_hi_lo(fa[e], h, l); ah[e] = h; al[e] = l; }
#pragma unroll
      for (int e = 0; e < 4; ++e) { short h, l; split_hi_lo(fb[e], h, l); ah[4+e] = h; al[4+e] = l; }
#pragma unroll
      for (int ni = 0; ni < 4; ++ni) {
        acc[mi][ni] = __builtin_amdgcn_mfma_f32_16x16x32_bf16(ah, bhf[ni], acc[mi][ni], 0, 0, 0);
        acc[mi][ni] = __builtin_amdgcn_mfma_f32_16x16x32_bf16(ah, blf[ni], acc[mi][ni], 0, 0, 0);
        acc[mi][ni] = __builtin_amdgcn_mfma_f32_16x16x32_bf16(al, bhf[ni], acc[mi][ni], 0, 0, 0);
      }
    }
  }

  // epilogue: bias, (pos+relu for k / relu for q), scatter to (B*H, N, 32)
  const int s = ct / 3, cb = (ct - s * 3) * 128;   // s: 0=q 1=k 2=v
  float* outp = (s == 0) ? qo : ((s == 1) ? ko : vo);
  float biasv[4];
#pragma unroll
  for (int ni = 0; ni < 4; ++ni) biasv[ni] = bias[t0 + wn + ni * 16 + l15];
#pragma unroll
  for (int mi = 0; mi < 4; ++mi) {
#pragma unroll
    for (int rr = 0; rr < 4; ++rr) {
      int m = m0 + wm + mi * 16 + l4 * 4 + rr;
      int b = m / 196, n = m - b * 196;
      size_t rowb = (size_t)b * 75264 + (size_t)n * 32;
#pragma unroll
      for (int ni = 0; ni < 4; ++ni) {
        int c = cb + wn + ni * 16 + l15;
        float val = acc[mi][ni][rr] + biasv[ni];
        if (s == 0) val = fmaxf(val, 0.f);
        if (s == 1) { val += pos[n * 384 + c]; val = fmaxf(val, 0.f); }
        outp[rowb + (size_t)(c >> 5) * 6272 + (c & 31)] = val;
      }
    }
  }
}

// ---------------- kernel 2: per-(b,h) linear attention + depthwise conv ----------------
// y = z*(q@kv) + dwconv5x5(v) + dwc_b ; y written over v's buffer (v snapshotted in LDS).
__global__ __launch_bounds__(256) void attn_conv(
    const float* __restrict__ q, const float* __restrict__ k,
    float* __restrict__ v,   // input v AND output y
    const float* __restrict__ dwc_w, const float* __restrict__ dwc_b)
{
  __shared__ __align__(16) float sk[NN * HD];
  __shared__ __align__(16) float sv[NN * HD];
  __shared__ __align__(16) float skv[32 * 36];
  __shared__ float red[8 * 32];
  __shared__ float sksum[32];
  __shared__ float swc[25 * 32];

  const int tid = threadIdx.x;
  const size_t base = (size_t)blockIdx.x * PH;
  const float* kp = k + base;
  const float* vp = v + base;
  const float* qp = q + base;
  float* yp = v + base;

  for (int i = tid; i < PH / 4; i += 256) {
    ((float4*)sk)[i] = ((const float4*)kp)[i];
    ((float4*)sv)[i] = ((const float4*)vp)[i];
  }
  for (int i = tid; i < 800; i += 256) {
    int d = i / 25, t = i - d * 25;
    swc[t * 32 + d] = dwc_w[i];                  // [tap][d]
  }
  __syncthreads();

  // kv[c][d] = sum_n k[n][c]*v[n][d]
  {
    int c = tid >> 3, d0 = (tid & 7) * 4;
    float a0 = 0, a1 = 0, a2 = 0, a3 = 0;
    for (int n = 0; n < NN; ++n) {
      float kc = sk[n * 32 + c];
      const float4 vv = *(const float4*)&sv[n * 32 + d0];
      a0 += kc * vv.x; a1 += kc * vv.y; a2 += kc * vv.z; a3 += kc * vv.w;
    }
    float4 r4; r4.x = a0; r4.y = a1; r4.z = a2; r4.w = a3;
    *(float4*)&skv[c * 36 + d0] = r4;
  }
  // ksum partials
  {
    int c = tid & 31, seg = tid >> 5;
    float s = 0;
    for (int n = seg; n < NN; n += 8) s += sk[n * 32 + c];
    red[seg * 32 + c] = s;
  }
  __syncthreads();
  if (tid < 32) {
    float s = 0;
#pragma unroll
    for (int j = 0; j < 8; ++j) s += red[j * 32 + tid];
    sksum[tid] = s;
  }
  __syncthreads();

  const int lane = tid & 63, wv4 = tid >> 6;
  const int d = lane & 31, half = lane >> 5;
  const float ks_d = sksum[d];
  const float bias_d = dwc_b[d];
  float wreg[25];
#pragma unroll
  for (int t = 0; t < 25; ++t) wreg[t] = swc[t * 32 + d];
  const int sbase = lane & 32;

  for (int n = wv4 * 2 + half; n < NN; n += 8) {
    float qv = qp[n * 32 + d];
    float p = qv * ks_d;
#pragma unroll
    for (int off = 16; off >= 1; off >>= 1) p += __shfl_xor(p, off);
    float z = 1.f / (p + 1e-6f);
    float o0 = 0, o1 = 0;
#pragma unroll
    for (int c = 0; c < 32; c += 2) {
      o0 += __shfl(qv, sbase + c)     * skv[c * 36 + d];
      o1 += __shfl(qv, sbase + c + 1) * skv[(c + 1) * 36 + d];
    }
    float o = (o0 + o1) * z;
    int py = n / 14, px = n - py * 14;
    float fm = bias_d;
#pragma unroll
    for (int ky = 0; ky < 5; ++ky) {
      int yy = py + ky - 2;
      if (yy < 0 || yy >= 14) continue;
#pragma unroll
      for (int kx = 0; kx < 5; ++kx) {
        int xx = px + kx - 2;
        if (xx < 0 || xx >= 14) continue;
        fm += sv[(yy * 14 + xx) * 32 + d] * wreg[ky * 5 + kx];
      }
    }
    yp[n * 32 + d] = o + fm;
  }
}

// ---------------- kernel 3: out = y @ proj_w^T + proj_b ----------------
__global__ __launch_bounds__(256, 2) void proj_gemm(
    const float* __restrict__ yv, const u16* __restrict__ wh, const u16* __restrict__ wl,
    const float* __restrict__ bias, float* __restrict__ out)
{
  __shared__ __align__(16) char lds[2][32768];
  const int tid  = threadIdx.x;
  const int lane = tid & 63, wv = tid >> 6;
  const int L  = ((int)blockIdx.x & 7) * 588 + ((int)blockIdx.x >> 3);  // 4704 = 8*588
  const int rt = L / 3, ct = L - rt * 3;
  const int m0 = rt * 128, t0 = ct * 128;

  // A source: permuted gather from head-split y buffer
  u32 a_rowb[4]; int a_d[4];
  {
    int sg = lane & 7, lr = lane >> 3;
#pragma unroll
    for (int j = 0; j < 4; ++j) {
      int r = (wv * 4 + j) * 8 + lr;
      int m = m0 + r;
      int b = m / 196, n = m - b * 196;
      a_rowb[j] = (u32)b * 75264u + (u32)n * 32u;
      a_d[j] = (sg ^ (r & 7)) * 4;
    }
  }
  const u16 *bh_src[2], *bl_src[2];
#pragma unroll
  for (int j = 0; j < 2; ++j) {
    int gi = (wv * 2 + j) * 64 + lane;
    int kb = gi >> 7, t = gi & 127;
    size_t o = (size_t)(t0 + t) * NC + kb * 8;
    bh_src[j] = wh + o;
    bl_src[j] = wl + o;
  }

  auto stage = [&](char* buf, int kh) {   // kh = K-step index (32 cols = head kh)
#pragma unroll
    for (int j = 0; j < 4; ++j)
      gload_lds16(yv + a_rowb[j] + (size_t)kh * 6272 + a_d[j], buf + (wv * 4 + j) * 1024);
#pragma unroll
    for (int j = 0; j < 2; ++j) {
      gload_lds16(bh_src[j] + kh * 32, buf + 16384 + (wv * 2 + j) * 1024);
      gload_lds16(bl_src[j] + kh * 32, buf + 24576 + (wv * 2 + j) * 1024);
    }
  };

  const int wm = (wv & 1) * 64, wn = (wv >> 1) * 64;
  const int l15 = lane & 15, l4 = lane >> 4;
  int boff[4], aoff0[4], aoff1[4];
#pragma unroll
  for (int i = 0; i < 4; ++i) {
    boff[i] = (l4 * 128 + wn + i * 16 + l15) * 16;
    int r = wm + i * 16 + l15;
    aoff0[i] = r * 128 + (((l4 * 2)     ^ (r & 7)) * 16);
    aoff1[i] = r * 128 + (((l4 * 2 + 1) ^ (r & 7)) * 16);
  }

  f4 acc[4][4];
  const f4 fz = {0.f, 0.f, 0.f, 0.f};
#pragma unroll
  for (int i = 0; i < 4; ++i)
#pragma unroll
    for (int j = 0; j < 4; ++j) acc[i][j] = fz;

  stage(lds[0], 0);
  for (int kt = 0; kt < 12; ++kt) {
    __syncthreads();
    if (kt < 11) stage(lds[(kt + 1) & 1], kt + 1);
    char* buf = lds[kt & 1];
    bx8 bhf[4], blf[4];
#pragma unroll
    for (int i = 0; i < 4; ++i) {
      bhf[i] = *(const bx8*)(buf + 16384 + boff[i]);
      blf[i] = *(const bx8*)(buf + 24576 + boff[i]);
    }
#pragma unroll
    for (int mi = 0; mi < 4; ++mi) {
      f4 fa = *(const f4*)(buf + aoff0[mi]);
      f4 fb = *(const f4*)(buf + aoff1[mi]);
      bx8 ah, al;
#pragma unroll
      for (int e = 0; e < 4; ++e) { short h, l; split_hi_lo(fa[e], h, l); ah[e] = h; al[e] = l; }
#pragma unroll
      for (int e = 0; e < 4; ++e) { short h, l; split_hi_lo(fb[e], h, l); ah[4+e] = h; al[4+e] = l; }
#pragma unroll
      for (int ni = 0; ni < 4; ++ni) {
        acc[mi][ni] = __builtin_amdgcn_mfma_f32_16x16x32_bf16(ah, bhf[ni], acc[mi][ni], 0, 0, 0);
        acc[mi][ni] = __builtin_amdgcn_mfma_f32_16x16x32_bf16(ah, blf[ni], acc[mi][ni], 0, 0, 0);
        acc[mi][ni] = __builtin_amdgcn_mfma_f32_16x16x32_bf16(al, bhf[ni], acc[mi][ni], 0, 0, 0);
      }
    }
  }

  float biasv[4];
#pragma unroll
  for (int ni = 0; ni < 4; ++ni) biasv[ni] = bias[t0 + wn + ni * 16 + l15];
#pragma unroll
  for (int mi = 0; mi < 4; ++mi) {
#pragma unroll
    for (int rr = 0; rr < 4; ++rr) {
      int m = m0 + wm + mi * 16 + l4 * 4 + rr;
      size_t ob = (size_t)m * 384 + t0 + wn;
#pragma unroll
      for (int ni = 0; ni < 4; ++ni)
        out[ob + ni * 16 + l15] = acc[mi][ni][rr] + biasv[ni];
    }
  }
}

// ---------------- launcher ----------------
extern "C" void kernel_launch(void* const* d_in, const int* in_sizes, int n_in,
                              void* d_out, int out_size, void* d_ws, size_t ws_size,
                              hipStream_t stream)
{
  const float* x      = (const float*)d_in[0];
  const float* qkv_w  = (const float*)d_in[1];
  const float* qkv_b  = (const float*)d_in[2];
  const float* proj_w = (const float*)d_in[3];
  const float* proj_b = (const float*)d_in[4];
  const float* dwc_w  = (const float*)d_in[5];
  const float* dwc_b  = (const float*)d_in[6];
  const float* pos    = (const float*)d_in[7];
  float* out = (float*)d_out;

  char* ws = (char*)d_ws;
  float* qb = (float*)(ws + OFF_Q);
  float* kb = (float*)(ws + OFF_K);
  float* vb = (float*)(ws + OFF_V);
  u16* wqh = (u16*)(ws + OFF_WQH);
  u16* wql = (u16*)(ws + OFF_WQL);
  u16* wph = (u16*)(ws + OFF_WPH);
  u16* wpl = (u16*)(ws + OFF_WPL);

  split_weights<<<1728, 256, 0, stream>>>(qkv_w, proj_w, wqh, wql, wph, wpl);
  qkv_gemm<<<14112, 256, 0, stream>>>(x, wqh, wql, qkv_b, pos, qb, kb, vb);
  attn_conv<<<12288, 256, 0, stream>>>(qb, kb, vb, dwc_w, dwc_b);
  proj_gemm<<<4704, 256, 0, stream>>>(vb, wph, wpl, proj_b, out);
}

// Round 2
// 1566.227 us; speedup vs baseline: 1.5257x; 1.5257x over previous
//
#include <hip/hip_runtime.h>
#include <cstdint>

#define DI __device__ __forceinline__

typedef __attribute__((ext_vector_type(8))) short bx8;   // 8 x bf16 (bit pattern)
typedef __attribute__((ext_vector_type(4))) float f4;
typedef __attribute__((ext_vector_type(2))) float f2;
typedef unsigned short u16;
typedef unsigned int u32;
typedef __attribute__((ext_vector_type(4))) u32 u32x4;

// ---------------- problem constants ----------------
constexpr int NB = 1024;         // batch
constexpr int NN = 196;          // tokens
constexpr int NC = 384;          // channels
constexpr int NH = 12;           // heads
constexpr int HD = 32;           // head dim
constexpr int C3 = 3 * NC;       // 1152
constexpr int PH = NN * HD;      // 6272 elements per (b,h)

// workspace layout (bytes)
constexpr size_t SZ_T    = (size_t)NB * NH * PH * 4;   // 308,281,344 per tensor
constexpr size_t OFF_Q   = 0;
constexpr size_t OFF_K   = SZ_T;
constexpr size_t OFF_V   = 2 * SZ_T;                   // v, later reused as y
constexpr size_t OFF_WQH = 3 * SZ_T;
constexpr size_t SZ_WQ   = (size_t)C3 * NC * 2;        // 884,736
constexpr size_t OFF_WQL = OFF_WQH + SZ_WQ;
constexpr size_t OFF_WPH = OFF_WQL + SZ_WQ;
constexpr size_t SZ_WP   = (size_t)NC * NC * 2;        // 294,912
constexpr size_t OFF_WPL = OFF_WPH + SZ_WP;

DI void gload_lds16(const void* g, void* l) {
  using GP = const void __attribute__((address_space(1)))*;
  using LP = void __attribute__((address_space(3)))*;
  __builtin_amdgcn_global_load_lds((GP)g, (LP)l, 16, 0, 0);
}

// split fp32 into bf16 hi (bit-truncate) + bf16 lo (truncated residual)
DI void split_hi_lo(float f, short& hi, short& lo) {
  u32 u = __float_as_uint(f);
  hi = (short)(u >> 16);
  float l = f - __uint_as_float(u & 0xffff0000u);   // exact (Sterbenz)
  lo = (short)(__float_as_uint(l) >> 16);
}

DI u32 cvt_pk_bf16(float lo, float hi) {   // dst = bf16(lo) | bf16(hi)<<16, RNE
  u32 r;
  asm volatile("v_cvt_pk_bf16_f32 %0, %1, %2" : "=v"(r) : "v"(lo), "v"(hi));
  return r;
}
DI float bflo(u32 p) { return __uint_as_float(p << 16); }
DI float bfhi(u32 p) { return __uint_as_float(p & 0xffff0000u); }

// ---------------- kernel 0: pre-split weight matrices ----------------
__global__ void split_weights(const float* __restrict__ qw, const float* __restrict__ pw,
                              u16* __restrict__ qh, u16* __restrict__ ql,
                              u16* __restrict__ ph, u16* __restrict__ pl)
{
  int i = blockIdx.x * 256 + threadIdx.x;
  if (i < C3 * NC) {
    float f = qw[i];
    u32 u = __float_as_uint(f);
    qh[i] = (u16)(u >> 16);
    float lo = f - __uint_as_float(u & 0xffff0000u);
    u32 ul = __float_as_uint(lo);
    ul += 0x7fffu + ((ul >> 16) & 1u);               // RNE on residual
    ql[i] = (u16)(ul >> 16);
  }
  if (i < NC * NC) {
    float f = pw[i];
    u32 u = __float_as_uint(f);
    ph[i] = (u16)(u >> 16);
    float lo = f - __uint_as_float(u & 0xffff0000u);
    u32 ul = __float_as_uint(lo);
    ul += 0x7fffu + ((ul >> 16) & 1u);
    pl[i] = (u16)(ul >> 16);
  }
}

// ---------------- kernel 1: qkv = x @ qkv_w^T + b ; relu/pos ; head-split ----------------
__global__ __launch_bounds__(256, 2) void qkv_gemm(
    const float* __restrict__ x, const u16* __restrict__ wh, const u16* __restrict__ wl,
    const float* __restrict__ bias, const float* __restrict__ pos,
    float* __restrict__ qo, float* __restrict__ ko, float* __restrict__ vo)
{
  __shared__ __align__(16) char lds[2][32768];   // A fp32 16K | Bh 8K | Bl 8K
  const int tid  = threadIdx.x;
  const int lane = tid & 63, wv = tid >> 6;
  const int L  = ((int)blockIdx.x & 7) * 1764 + ((int)blockIdx.x >> 3); // XCD swizzle (14112=8*1764)
  const int rt = L / 9, ct = L - rt * 9;
  const int m0 = rt * 128, t0 = ct * 128;

  const float* a_src[4];
  {
    int sg = lane & 7, lr = lane >> 3;
#pragma unroll
    for (int j = 0; j < 4; ++j) {
      int r = (wv * 4 + j) * 8 + lr;
      int g = sg ^ (r & 7);
      a_src[j] = x + (size_t)(m0 + r) * NC + g * 4;
    }
  }
  const u16 *bh_src[2], *bl_src[2];
#pragma unroll
  for (int j = 0; j < 2; ++j) {
    int gi = (wv * 2 + j) * 64 + lane;
    int kb = gi >> 7, t = gi & 127;
    size_t o = (size_t)(t0 + t) * NC + kb * 8;
    bh_src[j] = wh + o;
    bl_src[j] = wl + o;
  }

  auto stage = [&](char* buf, int k0) {
#pragma unroll
    for (int j = 0; j < 4; ++j)
      gload_lds16(a_src[j] + k0, buf + (wv * 4 + j) * 1024);
#pragma unroll
    for (int j = 0; j < 2; ++j) {
      gload_lds16(bh_src[j] + k0, buf + 16384 + (wv * 2 + j) * 1024);
      gload_lds16(bl_src[j] + k0, buf + 24576 + (wv * 2 + j) * 1024);
    }
  };

  const int wm = (wv & 1) * 64, wn = (wv >> 1) * 64;
  const int l15 = lane & 15, l4 = lane >> 4;
  int boff[4], aoff0[4], aoff1[4];
#pragma unroll
  for (int i = 0; i < 4; ++i) {
    boff[i] = (l4 * 128 + wn + i * 16 + l15) * 16;
    int r = wm + i * 16 + l15;
    aoff0[i] = r * 128 + (((l4 * 2)     ^ (r & 7)) * 16);
    aoff1[i] = r * 128 + (((l4 * 2 + 1) ^ (r & 7)) * 16);
  }

  f4 acc[4][4];
  const f4 fz = {0.f, 0.f, 0.f, 0.f};
#pragma unroll
  for (int i = 0; i < 4; ++i)
#pragma unroll
    for (int j = 0; j < 4; ++j) acc[i][j] = fz;

  stage(lds[0], 0);
  for (int kt = 0; kt < 12; ++kt) {
    __syncthreads();
    if (kt < 11) stage(lds[(kt + 1) & 1], (kt + 1) * 32);
    char* buf = lds[kt & 1];
    bx8 bhf[4], blf[4];
#pragma unroll
    for (int i = 0; i < 4; ++i) {
      bhf[i] = *(const bx8*)(buf + 16384 + boff[i]);
      blf[i] = *(const bx8*)(buf + 24576 + boff[i]);
    }
#pragma unroll
    for (int mi = 0; mi < 4; ++mi) {
      f4 fa = *(const f4*)(buf + aoff0[mi]);
      f4 fb = *(const f4*)(buf + aoff1[mi]);
      bx8 ah, al;
#pragma unroll
      for (int e = 0; e < 4; ++e) { short h, l; split_hi_lo(fa[e], h, l); ah[e] = h; al[e] = l; }
#pragma unroll
      for (int e = 0; e < 4; ++e) { short h, l; split_hi_lo(fb[e], h, l); ah[4+e] = h; al[4+e] = l; }
#pragma unroll
      for (int ni = 0; ni < 4; ++ni) {
        acc[mi][ni] = __builtin_amdgcn_mfma_f32_16x16x32_bf16(ah, bhf[ni], acc[mi][ni], 0, 0, 0);
        acc[mi][ni] = __builtin_amdgcn_mfma_f32_16x16x32_bf16(ah, blf[ni], acc[mi][ni], 0, 0, 0);
        acc[mi][ni] = __builtin_amdgcn_mfma_f32_16x16x32_bf16(al, bhf[ni], acc[mi][ni], 0, 0, 0);
      }
    }
  }

  const int s = ct / 3, cb = (ct - s * 3) * 128;   // s: 0=q 1=k 2=v
  float* outp = (s == 0) ? qo : ((s == 1) ? ko : vo);
  float biasv[4];
#pragma unroll
  for (int ni = 0; ni < 4; ++ni) biasv[ni] = bias[t0 + wn + ni * 16 + l15];
#pragma unroll
  for (int mi = 0; mi < 4; ++mi) {
#pragma unroll
    for (int rr = 0; rr < 4; ++rr) {
      int m = m0 + wm + mi * 16 + l4 * 4 + rr;
      int b = m / 196, n = m - b * 196;
      size_t rowb = (size_t)b * 75264 + (size_t)n * 32;
#pragma unroll
      for (int ni = 0; ni < 4; ++ni) {
        int c = cb + wn + ni * 16 + l15;
        float val = acc[mi][ni][rr] + biasv[ni];
        if (s == 0) val = fmaxf(val, 0.f);
        if (s == 1) { val += pos[n * 384 + c]; val = fmaxf(val, 0.f); }
        outp[rowb + (size_t)(c >> 5) * 6272 + (c & 31)] = val;
      }
    }
  }
}

// ---------------- kernel 2: per-(b,h) linear attention + depthwise conv ----------------
// Rewritten: minimal DS-pipe traffic, 36KB LDS -> 4 blocks/CU.
// phases: [stage v->bf16 LDS] S [kv 8-way n-split + shfl reduce ; conv d-pair] S [out]
__global__ __launch_bounds__(256, 4) void attn_conv(
    const float* __restrict__ q, const float* __restrict__ k,
    const float* __restrict__ v, float* __restrict__ y,
    const float* __restrict__ dwc_w, const float* __restrict__ dwc_b)
{
  __shared__ __align__(16) u16  sv[NN * 40];    // bf16 v, rows padded to 40 (80B)
  __shared__ __align__(16) u16  sfm[NN * 40];   // bf16 conv output
  __shared__ __align__(16) float skv[32 * 36];  // kv fp32, row pad 36
  __shared__ float sksum[32];

  const int tid = threadIdx.x;
  const size_t base = (size_t)blockIdx.x * PH;
  const float* vp = v + base;
  const float* kp = k + base;
  const float* qp = q + base;
  float* yp = y + base;
  char* svb  = (char*)sv;
  char* sfmb = (char*)sfm;

  // ---- phase 1: stage v (fp32 global -> bf16 LDS, RNE) ----
  for (int c = tid; c < 784; c += 256) {       // 784 chunks of 8 floats
    f4 f0 = ((const f4*)vp)[c * 2];
    f4 f1 = ((const f4*)vp)[c * 2 + 1];
    u32x4 pk;
    pk[0] = cvt_pk_bf16(f0[0], f0[1]);
    pk[1] = cvt_pk_bf16(f0[2], f0[3]);
    pk[2] = cvt_pk_bf16(f1[0], f1[1]);
    pk[3] = cvt_pk_bf16(f1[2], f1[3]);
    *(u32x4*)(svb + (c >> 2) * 80 + (c & 3) * 16) = pk;
  }
  __syncthreads();

  // ---- phase 2: kv[c][d] = sum_n k[n][c]*v[n][d]  (8-way n-split + butterfly) ----
  {
    const int c = tid >> 3, ns = tid & 7;
    float acc[33];
#pragma unroll
    for (int d = 0; d < 33; ++d) acc[d] = 0.f;
    for (int i = 0; i < 25; ++i) {
      int n = i * 8 + ns;
      if (n < 196) {
        float kc = kp[n * 32 + c];           // global (coalesced 32B segments)
#pragma unroll
        for (int g = 0; g < 4; ++g) {
          u32x4 r = *(const u32x4*)(svb + n * 80 + g * 16);
#pragma unroll
          for (int j = 0; j < 4; ++j) {
            acc[g * 8 + 2 * j]     += kc * bflo(r[j]);
            acc[g * 8 + 2 * j + 1] += kc * bfhi(r[j]);
          }
        }
        acc[32] += kc;
      }
    }
#pragma unroll
    for (int off = 1; off <= 4; off <<= 1) {
#pragma unroll
      for (int d = 0; d < 33; ++d) acc[d] += __shfl_xor(acc[d], off);
    }
    if (ns == 0) {
#pragma unroll
      for (int d4 = 0; d4 < 32; d4 += 4) {
        f4 w; w[0] = acc[d4]; w[1] = acc[d4+1]; w[2] = acc[d4+2]; w[3] = acc[d4+3];
        *(f4*)&skv[c * 36 + d4] = w;
      }
      sksum[c] = acc[32];
    }
  }

  // ---- phase 3: depthwise 5x5 conv on v (d-pair threads), fm -> bf16 LDS ----
  {
    const int dp = tid & 15, py = tid >> 4;   // dp: d-pair, py: image row
    if (py < 14) {
      const int d0 = 2 * dp;
      float fm0[14], fm1[14];
      const float b0 = dwc_b[d0], b1 = dwc_b[d0 + 1];
#pragma unroll
      for (int px = 0; px < 14; ++px) { fm0[px] = b0; fm1[px] = b1; }
#pragma unroll
      for (int ky = 0; ky < 5; ++ky) {
        int yy = py + ky - 2;
        if (yy < 0 || yy >= 14) continue;
        float w0[5], w1[5];
#pragma unroll
        for (int t = 0; t < 5; ++t) {
          w0[t] = dwc_w[d0 * 25 + ky * 5 + t];
          w1[t] = dwc_w[(d0 + 1) * 25 + ky * 5 + t];
        }
        float r0[14], r1[14];
#pragma unroll
        for (int xx = 0; xx < 14; ++xx) {
          u32 pr = *(const u32*)(svb + (yy * 14 + xx) * 80 + dp * 4);
          r0[xx] = bflo(pr); r1[xx] = bfhi(pr);
        }
#pragma unroll
        for (int px = 0; px < 14; ++px) {
#pragma unroll
          for (int kx = 0; kx < 5; ++kx) {
            int xx = px + kx - 2;
            if (xx < 0 || xx > 13) continue;
            fm0[px] += w0[kx] * r0[xx];
            fm1[px] += w1[kx] * r1[xx];
          }
        }
      }
#pragma unroll
      for (int px = 0; px < 14; ++px)
        *(u32*)(sfmb + (py * 14 + px) * 80 + dp * 4) = cvt_pk_bf16(fm0[px], fm1[px]);
    }
  }
  __syncthreads();

  // ---- phase 4: out = z*(q@kv) + fm ; write y (fp32 global) ----
  {
    const int dp = tid & 15, ng = tid >> 4;
    const int d0 = 2 * dp;
    float kv0[32], kv1[32], ks[32];
#pragma unroll
    for (int c = 0; c < 32; ++c) {
      const float* p = &skv[c * 36 + d0];
      kv0[c] = p[0]; kv1[c] = p[1];
    }
#pragma unroll
    for (int c = 0; c < 32; ++c) ks[c] = sksum[c];
#pragma unroll 2
    for (int i = 0; i < 13; ++i) {
      int n = i * 16 + ng;
      if (n < 196) {
        float o0 = 0.f, o1 = 0.f, pz = 0.f;
#pragma unroll
        for (int c4 = 0; c4 < 32; c4 += 4) {
          f4 qv = *(const f4*)(qp + n * 32 + c4);
#pragma unroll
          for (int j = 0; j < 4; ++j) {
            o0 += qv[j] * kv0[c4 + j];
            o1 += qv[j] * kv1[c4 + j];
            pz += qv[j] * ks[c4 + j];
          }
        }
        float z = 1.f / (pz + 1e-6f);
        u32 fmp = *(const u32*)(sfmb + n * 80 + dp * 4);
        f2 r; r[0] = fmaf(o0, z, bflo(fmp)); r[1] = fmaf(o1, z, bfhi(fmp));
        *(f2*)(yp + n * 32 + d0) = r;
      }
    }
  }
}

// ---------------- kernel 3: out = y @ proj_w^T + proj_b ----------------
__global__ __launch_bounds__(256, 2) void proj_gemm(
    const float* __restrict__ yv, const u16* __restrict__ wh, const u16* __restrict__ wl,
    const float* __restrict__ bias, float* __restrict__ out)
{
  __shared__ __align__(16) char lds[2][32768];
  const int tid  = threadIdx.x;
  const int lane = tid & 63, wv = tid >> 6;
  const int L  = ((int)blockIdx.x & 7) * 588 + ((int)blockIdx.x >> 3);  // 4704 = 8*588
  const int rt = L / 3, ct = L - rt * 3;
  const int m0 = rt * 128, t0 = ct * 128;

  u32 a_rowb[4]; int a_d[4];
  {
    int sg = lane & 7, lr = lane >> 3;
#pragma unroll
    for (int j = 0; j < 4; ++j) {
      int r = (wv * 4 + j) * 8 + lr;
      int m = m0 + r;
      int b = m / 196, n = m - b * 196;
      a_rowb[j] = (u32)b * 75264u + (u32)n * 32u;
      a_d[j] = (sg ^ (r & 7)) * 4;
    }
  }
  const u16 *bh_src[2], *bl_src[2];
#pragma unroll
  for (int j = 0; j < 2; ++j) {
    int gi = (wv * 2 + j) * 64 + lane;
    int kb = gi >> 7, t = gi & 127;
    size_t o = (size_t)(t0 + t) * NC + kb * 8;
    bh_src[j] = wh + o;
    bl_src[j] = wl + o;
  }

  auto stage = [&](char* buf, int kh) {
#pragma unroll
    for (int j = 0; j < 4; ++j)
      gload_lds16(yv + a_rowb[j] + (size_t)kh * 6272 + a_d[j], buf + (wv * 4 + j) * 1024);
#pragma unroll
    for (int j = 0; j < 2; ++j) {
      gload_lds16(bh_src[j] + kh * 32, buf + 16384 + (wv * 2 + j) * 1024);
      gload_lds16(bl_src[j] + kh * 32, buf + 24576 + (wv * 2 + j) * 1024);
    }
  };

  const int wm = (wv & 1) * 64, wn = (wv >> 1) * 64;
  const int l15 = lane & 15, l4 = lane >> 4;
  int boff[4], aoff0[4], aoff1[4];
#pragma unroll
  for (int i = 0; i < 4; ++i) {
    boff[i] = (l4 * 128 + wn + i * 16 + l15) * 16;
    int r = wm + i * 16 + l15;
    aoff0[i] = r * 128 + (((l4 * 2)     ^ (r & 7)) * 16);
    aoff1[i] = r * 128 + (((l4 * 2 + 1) ^ (r & 7)) * 16);
  }

  f4 acc[4][4];
  const f4 fz = {0.f, 0.f, 0.f, 0.f};
#pragma unroll
  for (int i = 0; i < 4; ++i)
#pragma unroll
    for (int j = 0; j < 4; ++j) acc[i][j] = fz;

  stage(lds[0], 0);
  for (int kt = 0; kt < 12; ++kt) {
    __syncthreads();
    if (kt < 11) stage(lds[(kt + 1) & 1], kt + 1);
    char* buf = lds[kt & 1];
    bx8 bhf[4], blf[4];
#pragma unroll
    for (int i = 0; i < 4; ++i) {
      bhf[i] = *(const bx8*)(buf + 16384 + boff[i]);
      blf[i] = *(const bx8*)(buf + 24576 + boff[i]);
    }
#pragma unroll
    for (int mi = 0; mi < 4; ++mi) {
      f4 fa = *(const f4*)(buf + aoff0[mi]);
      f4 fb = *(const f4*)(buf + aoff1[mi]);
      bx8 ah, al;
#pragma unroll
      for (int e = 0; e < 4; ++e) { short h, l; split_hi_lo(fa[e], h, l); ah[e] = h; al[e] = l; }
#pragma unroll
      for (int e = 0; e < 4; ++e) { short h, l; split_hi_lo(fb[e], h, l); ah[4+e] = h; al[4+e] = l; }
#pragma unroll
      for (int ni = 0; ni < 4; ++ni) {
        acc[mi][ni] = __builtin_amdgcn_mfma_f32_16x16x32_bf16(ah, bhf[ni], acc[mi][ni], 0, 0, 0);
        acc[mi][ni] = __builtin_amdgcn_mfma_f32_16x16x32_bf16(ah, blf[ni], acc[mi][ni], 0, 0, 0);
        acc[mi][ni] = __builtin_amdgcn_mfma_f32_16x16x32_bf16(al, bhf[ni], acc[mi][ni], 0, 0, 0);
      }
    }
  }

  float biasv[4];
#pragma unroll
  for (int ni = 0; ni < 4; ++ni) biasv[ni] = bias[t0 + wn + ni * 16 + l15];
#pragma unroll
  for (int mi = 0; mi < 4; ++mi) {
#pragma unroll
    for (int rr = 0; rr < 4; ++rr) {
      int m = m0 + wm + mi * 16 + l4 * 4 + rr;
      size_t ob = (size_t)m * 384 + t0 + wn;
#pragma unroll
      for (int ni = 0; ni < 4; ++ni)
        out[ob + ni * 16 + l15] = acc[mi][ni][rr] + biasv[ni];
    }
  }
}

// ---------------- launcher ----------------
extern "C" void kernel_launch(void* const* d_in, const int* in_sizes, int n_in,
                              void* d_out, int out_size, void* d_ws, size_t ws_size,
                              hipStream_t stream)
{
  const float* x      = (const float*)d_in[0];
  const float* qkv_w  = (const float*)d_in[1];
  const float* qkv_b  = (const float*)d_in[2];
  const float* proj_w = (const float*)d_in[3];
  const float* proj_b = (const float*)d_in[4];
  const float* dwc_w  = (const float*)d_in[5];
  const float* dwc_b  = (const float*)d_in[6];
  const float* pos    = (const float*)d_in[7];
  float* out = (float*)d_out;

  char* ws = (char*)d_ws;
  float* qb = (float*)(ws + OFF_Q);
  float* kb = (float*)(ws + OFF_K);
  float* vb = (float*)(ws + OFF_V);
  u16* wqh = (u16*)(ws + OFF_WQH);
  u16* wql = (u16*)(ws + OFF_WQL);
  u16* wph = (u16*)(ws + OFF_WPH);
  u16* wpl = (u16*)(ws + OFF_WPL);

  split_weights<<<1728, 256, 0, stream>>>(qkv_w, proj_w, wqh, wql, wph, wpl);
  qkv_gemm<<<14112, 256, 0, stream>>>(x, wqh, wql, qkv_b, pos, qb, kb, vb);
  attn_conv<<<12288, 256, 0, stream>>>(qb, kb, vb, vb, dwc_w, dwc_b);
  proj_gemm<<<4704, 256, 0, stream>>>(vb, wph, wpl, proj_b, out);
}

// Round 3
// 1526.650 us; speedup vs baseline: 1.5653x; 1.0259x over previous
//
#include <hip/hip_runtime.h>
#include <cstdint>

#define DI __device__ __forceinline__

typedef __attribute__((ext_vector_type(8))) short bx8;   // 8 x bf16 (bit pattern)
typedef __attribute__((ext_vector_type(4))) float f4;
typedef __attribute__((ext_vector_type(2))) float f2;
typedef unsigned short u16;
typedef unsigned int u32;
typedef __attribute__((ext_vector_type(4))) u32 u32x4;

// ---------------- problem constants ----------------
constexpr int NB = 1024;         // batch
constexpr int NN = 196;          // tokens
constexpr int NC = 384;          // channels
constexpr int NH = 12;           // heads
constexpr int HD = 32;           // head dim
constexpr int C3 = 3 * NC;       // 1152
constexpr int PH = NN * HD;      // 6272 elements per (b,h)

// ======== main-path workspace layout (bytes) ========
constexpr size_t SZ_T    = (size_t)NB * NH * PH * 4;   // 308,281,344 (fp32 tensor)
constexpr size_t SZ_TH   = SZ_T / 2;                   // 154,140,672 (u16 tensor)
constexpr size_t OFF_Q   = 0;                          // q fp32
constexpr size_t OFF_K   = SZ_T;                       // k fp32 ; yh u16 overlays
constexpr size_t OFF_V   = 2 * SZ_T;                   // v bf16 ; yl u16 overlays
constexpr size_t OFF_WQH = OFF_V + SZ_TH;              // 770,703,360
constexpr size_t SZ_WQ   = (size_t)C3 * NC * 2;        // 884,736
constexpr size_t OFF_WQL = OFF_WQH + SZ_WQ;
constexpr size_t OFF_WPH = OFF_WQL + SZ_WQ;
constexpr size_t SZ_WP   = (size_t)NC * NC * 2;        // 294,912
constexpr size_t OFF_WPL = OFF_WPH + SZ_WP;
constexpr size_t OFF_XH  = OFF_WPL + SZ_WP;            // 773,062,656
constexpr size_t OFF_XL  = OFF_XH + SZ_TH;
constexpr size_t NEED_MAIN = OFF_XL + SZ_TH;           // 1,081,344,000

// ======== fallback (round-2) workspace layout ========
constexpr size_t OFF_Q_FB   = 0;
constexpr size_t OFF_K_FB   = SZ_T;
constexpr size_t OFF_V_FB   = 2 * SZ_T;
constexpr size_t OFF_WQH_FB = 3 * SZ_T;
constexpr size_t OFF_WQL_FB = OFF_WQH_FB + SZ_WQ;
constexpr size_t OFF_WPH_FB = OFF_WQL_FB + SZ_WQ;
constexpr size_t OFF_WPL_FB = OFF_WPH_FB + SZ_WP;

DI void gload_lds16(const void* g, void* l) {
  using GP = const void __attribute__((address_space(1)))*;
  using LP = void __attribute__((address_space(3)))*;
  __builtin_amdgcn_global_load_lds((GP)g, (LP)l, 16, 0, 0);
}

DI void split_hi_lo(float f, short& hi, short& lo) {
  u32 u = __float_as_uint(f);
  hi = (short)(u >> 16);
  float l = f - __uint_as_float(u & 0xffff0000u);   // exact
  lo = (short)(__float_as_uint(l) >> 16);
}

DI u32 cvt_pk_bf16(float lo, float hi) {   // dst = bf16(lo) | bf16(hi)<<16, RNE
  u32 r;
  asm volatile("v_cvt_pk_bf16_f32 %0, %1, %2" : "=v"(r) : "v"(lo), "v"(hi));
  return r;
}
DI float bflo(u32 p) { return __uint_as_float(p << 16); }
DI float bfhi(u32 p) { return __uint_as_float(p & 0xffff0000u); }

// ---------------- kernel: pre-split weight matrices (both paths) ----------------
__global__ void split_weights(const float* __restrict__ qw, const float* __restrict__ pw,
                              u16* __restrict__ qh, u16* __restrict__ ql,
                              u16* __restrict__ ph, u16* __restrict__ pl)
{
  int i = blockIdx.x * 256 + threadIdx.x;
  if (i < C3 * NC) {
    float f = qw[i];
    u32 u = __float_as_uint(f);
    qh[i] = (u16)(u >> 16);
    float lo = f - __uint_as_float(u & 0xffff0000u);
    u32 ul = __float_as_uint(lo);
    ul += 0x7fffu + ((ul >> 16) & 1u);               // RNE on residual
    ql[i] = (u16)(ul >> 16);
  }
  if (i < NC * NC) {
    float f = pw[i];
    u32 u = __float_as_uint(f);
    ph[i] = (u16)(u >> 16);
    float lo = f - __uint_as_float(u & 0xffff0000u);
    u32 ul = __float_as_uint(lo);
    ul += 0x7fffu + ((ul >> 16) & 1u);
    pl[i] = (u16)(ul >> 16);
  }
}

// ---------------- kernel: pre-split x into bf16 hi/lo ----------------
__global__ void split_x(const float* __restrict__ x, u16* __restrict__ xh, u16* __restrict__ xl)
{
  size_t i = ((size_t)blockIdx.x * 256 + threadIdx.x) * 8;
  f4 a = *(const f4*)(x + i);
  f4 b = *(const f4*)(x + i + 4);
  float v[8] = {a[0], a[1], a[2], a[3], b[0], b[1], b[2], b[3]};
  u32x4 hp, lp;
#pragma unroll
  for (int j = 0; j < 4; ++j) {
    float v0 = v[2 * j], v1 = v[2 * j + 1];
    u32 u0 = __float_as_uint(v0), u1 = __float_as_uint(v1);
    hp[j] = (u0 >> 16) | (u1 & 0xffff0000u);
    float l0 = v0 - __uint_as_float(u0 & 0xffff0000u);
    float l1 = v1 - __uint_as_float(u1 & 0xffff0000u);
    lp[j] = cvt_pk_bf16(l0, l1);
  }
  *(u32x4*)(xh + i) = hp;
  *(u32x4*)(xl + i) = lp;
}

// ================= MAIN PATH =================
// GEMM tiles: [128 rows][128B] per matrix region; bytes 0-63 = hi(k0..31), 64-127 = lo.
// st_16x32 swizzle: byte bit5 ^= byte bit9 (granule bit1 ^= row bit2). Linear LDS dest
// via global_load_lds; inverse-swizzle applied on per-lane GLOBAL source (rule 21).

// ---------------- kernel 1m: qkv = x @ qkv_w^T + b ; relu/pos ; head-split ----------------
__global__ __launch_bounds__(256, 2) void qkv_gemm(
    const u16* __restrict__ xh, const u16* __restrict__ xl,
    const u16* __restrict__ wh, const u16* __restrict__ wl,
    const float* __restrict__ bias, const float* __restrict__ pos,
    float* __restrict__ qo, float* __restrict__ ko, u16* __restrict__ vo)
{
  __shared__ __align__(16) char lds[2][32768];   // A 16K | B 16K
  const int tid  = threadIdx.x;
  const int lane = tid & 63, wv = tid >> 6;
  const int L  = ((int)blockIdx.x & 7) * 1764 + ((int)blockIdx.x >> 3); // 14112 = 8*1764
  const int rt = L / 9, ct = L - rt * 9;
  const int m0 = rt * 128, t0 = ct * 128;

  // staging sources: granule g = jj*256+tid ; region A (jj<4) rows jj*32+(tid>>3),
  // region B (jj>=4) rows (jj-4)*32+(tid>>3). c8s = inverse-swizzled column-granule.
  const int srow = tid >> 3;
  const int c8s  = (tid & 7) ^ (2 * ((tid >> 5) & 1));
  const int doff = (c8s & 3) * 8;
  const u16* sp[8];
#pragma unroll
  for (int jj = 0; jj < 4; ++jj) {
    const u16* basep = (c8s < 4) ? xh : xl;
    sp[jj] = basep + (size_t)(m0 + jj * 32 + srow) * NC + doff;
  }
#pragma unroll
  for (int jj = 4; jj < 8; ++jj) {
    const u16* basep = (c8s < 4) ? wh : wl;
    sp[jj] = basep + (size_t)(t0 + (jj - 4) * 32 + srow) * NC + doff;
  }

  auto stage = [&](char* buf) {
#pragma unroll
    for (int jj = 0; jj < 8; ++jj) {
      gload_lds16(sp[jj], buf + jj * 4096 + tid * 16);
      sp[jj] += 32;                                   // next K-step (32 u16)
    }
  };

  const int wm = (wv & 1) * 64, wn = (wv >> 1) * 64;
  const int l15 = lane & 15, l4 = lane >> 4;
  const int xb = 2 * ((l15 >> 2) & 1);                // swizzle bit (row bit2 = l15 bit2)
  int aoff[4], boff[4];
#pragma unroll
  for (int i = 0; i < 4; ++i) {
    int r = wm + i * 16 + l15;
    aoff[i] = r * 128 + ((l4 ^ xb) * 16);
    int t = wn + i * 16 + l15;
    boff[i] = t * 128 + ((l4 ^ xb) * 16);
  }

  f4 acc[4][4];
  const f4 fz = {0.f, 0.f, 0.f, 0.f};
#pragma unroll
  for (int i = 0; i < 4; ++i)
#pragma unroll
    for (int j = 0; j < 4; ++j) acc[i][j] = fz;

  stage(lds[0]);
  for (int kt = 0; kt < 12; ++kt) {
    __syncthreads();
    if (kt < 11) stage(lds[(kt + 1) & 1]);
    char* bufA = lds[kt & 1];
    char* bufB = bufA + 16384;
    bx8 ah[4], al[4], bh4[4], bl4[4];
#pragma unroll
    for (int i = 0; i < 4; ++i) {
      ah[i]  = *(const bx8*)(bufA + aoff[i]);
      al[i]  = *(const bx8*)(bufA + aoff[i] + 64);
      bh4[i] = *(const bx8*)(bufB + boff[i]);
      bl4[i] = *(const bx8*)(bufB + boff[i] + 64);
    }
#pragma unroll
    for (int mi = 0; mi < 4; ++mi)
#pragma unroll
      for (int ni = 0; ni < 4; ++ni) {
        acc[mi][ni] = __builtin_amdgcn_mfma_f32_16x16x32_bf16(ah[mi], bh4[ni], acc[mi][ni], 0, 0, 0);
        acc[mi][ni] = __builtin_amdgcn_mfma_f32_16x16x32_bf16(ah[mi], bl4[ni], acc[mi][ni], 0, 0, 0);
        acc[mi][ni] = __builtin_amdgcn_mfma_f32_16x16x32_bf16(al[mi], bh4[ni], acc[mi][ni], 0, 0, 0);
      }
  }

  // epilogue: bias, relu (q), pos+relu (k), bf16-RNE (v); head-split scatter
  const int s = ct / 3, cb = (ct - s * 3) * 128;   // s: 0=q 1=k 2=v
  float biasv[4];
#pragma unroll
  for (int ni = 0; ni < 4; ++ni) biasv[ni] = bias[t0 + wn + ni * 16 + l15];
#pragma unroll
  for (int mi = 0; mi < 4; ++mi) {
#pragma unroll
    for (int rr = 0; rr < 4; ++rr) {
      int m = m0 + wm + mi * 16 + l4 * 4 + rr;
      int b = m / 196, n = m - b * 196;
      size_t rowb = (size_t)b * 75264 + (size_t)n * 32;
#pragma unroll
      for (int ni = 0; ni < 4; ++ni) {
        int c = cb + wn + ni * 16 + l15;
        float val = acc[mi][ni][rr] + biasv[ni];
        size_t idx = rowb + (size_t)(c >> 5) * 6272 + (c & 31);
        if (s == 0) { qo[idx] = fmaxf(val, 0.f); }
        else if (s == 1) { ko[idx] = fmaxf(val + pos[n * 384 + c], 0.f); }
        else { vo[idx] = (u16)cvt_pk_bf16(val, val); }   // RNE bf16 (same as old attn cvt)
      }
    }
  }
}

// ---------------- kernel 2m: per-(b,h) linear attention + depthwise conv ----------------
// v input is bf16; y written pre-split: yh (trunc) -> K buffer, yl (RNE resid) -> V buffer.
// Safe: k fully consumed in phase 2, v fully consumed in phase 1, both before last barrier.
__global__ __launch_bounds__(256, 4) void attn_conv(
    const float* __restrict__ q, const float* k,
    const u16* v16, u16* yh, u16* yl,
    const float* __restrict__ dwc_w, const float* __restrict__ dwc_b)
{
  __shared__ __align__(16) u16  sv[NN * 40];    // bf16 v, rows padded to 40 (80B)
  __shared__ __align__(16) u16  sfm[NN * 40];   // bf16 conv output
  __shared__ __align__(16) float skv[32 * 36];  // kv fp32, row pad 36
  __shared__ float sksum[32];

  const int tid = threadIdx.x;
  const size_t base = (size_t)blockIdx.x * PH;
  const u16*   vp = v16 + base;
  const float* kp = k + base;
  const float* qp = q + base;
  u16* yhp = yh + base;
  u16* ylp = yl + base;
  char* svb  = (char*)sv;
  char* sfmb = (char*)sfm;

  // ---- phase 1: stage v bf16 -> padded LDS ----
  for (int c = tid; c < 784; c += 256) {        // 784 chunks of 16B (8 d's)
    u32x4 pk = *(const u32x4*)(vp + c * 8);
    *(u32x4*)(svb + (c >> 2) * 80 + (c & 3) * 16) = pk;
  }
  __syncthreads();

  // ---- phase 2: kv[c][d] = sum_n k[n][c]*v[n][d]  (8-way n-split + butterfly) ----
  {
    const int c = tid >> 3, ns = tid & 7;
    float acc[33];
#pragma unroll
    for (int d = 0; d < 33; ++d) acc[d] = 0.f;
    for (int i = 0; i < 25; ++i) {
      int n = i * 8 + ns;
      if (n < 196) {
        float kc = kp[n * 32 + c];
#pragma unroll
        for (int g = 0; g < 4; ++g) {
          u32x4 r = *(const u32x4*)(svb + n * 80 + g * 16);
#pragma unroll
          for (int j = 0; j < 4; ++j) {
            acc[g * 8 + 2 * j]     += kc * bflo(r[j]);
            acc[g * 8 + 2 * j + 1] += kc * bfhi(r[j]);
          }
        }
        acc[32] += kc;
      }
    }
#pragma unroll
    for (int off = 1; off <= 4; off <<= 1) {
#pragma unroll
      for (int d = 0; d < 33; ++d) acc[d] += __shfl_xor(acc[d], off);
    }
    if (ns == 0) {
#pragma unroll
      for (int d4 = 0; d4 < 32; d4 += 4) {
        f4 w; w[0] = acc[d4]; w[1] = acc[d4+1]; w[2] = acc[d4+2]; w[3] = acc[d4+3];
        *(f4*)&skv[c * 36 + d4] = w;
      }
      sksum[c] = acc[32];
    }
  }

  // ---- phase 3: depthwise 5x5 conv on v (d-pair threads), fm -> bf16 LDS ----
  {
    const int dp = tid & 15, py = tid >> 4;
    if (py < 14) {
      const int d0 = 2 * dp;
      float fm0[14], fm1[14];
      const float b0 = dwc_b[d0], b1 = dwc_b[d0 + 1];
#pragma unroll
      for (int px = 0; px < 14; ++px) { fm0[px] = b0; fm1[px] = b1; }
#pragma unroll
      for (int ky = 0; ky < 5; ++ky) {
        int yy = py + ky - 2;
        if (yy < 0 || yy >= 14) continue;
        float w0[5], w1[5];
#pragma unroll
        for (int t = 0; t < 5; ++t) {
          w0[t] = dwc_w[d0 * 25 + ky * 5 + t];
          w1[t] = dwc_w[(d0 + 1) * 25 + ky * 5 + t];
        }
        float r0[14], r1[14];
#pragma unroll
        for (int xx = 0; xx < 14; ++xx) {
          u32 pr = *(const u32*)(svb + (yy * 14 + xx) * 80 + dp * 4);
          r0[xx] = bflo(pr); r1[xx] = bfhi(pr);
        }
#pragma unroll
        for (int px = 0; px < 14; ++px) {
#pragma unroll
          for (int kx = 0; kx < 5; ++kx) {
            int xx = px + kx - 2;
            if (xx < 0 || xx > 13) continue;
            fm0[px] += w0[kx] * r0[xx];
            fm1[px] += w1[kx] * r1[xx];
          }
        }
      }
#pragma unroll
      for (int px = 0; px < 14; ++px)
        *(u32*)(sfmb + (py * 14 + px) * 80 + dp * 4) = cvt_pk_bf16(fm0[px], fm1[px]);
    }
  }
  __syncthreads();

  // ---- phase 4: y = z*(q@kv) + fm ; write split yh/yl ----
  {
    const int dp = tid & 15, ng = tid >> 4;
    const int d0 = 2 * dp;
    float kv0[32], kv1[32], ks[32];
#pragma unroll
    for (int c = 0; c < 32; ++c) {
      const float* p = &skv[c * 36 + d0];
      kv0[c] = p[0]; kv1[c] = p[1];
    }
#pragma unroll
    for (int c = 0; c < 32; ++c) ks[c] = sksum[c];
#pragma unroll 2
    for (int i = 0; i < 13; ++i) {
      int n = i * 16 + ng;
      if (n < 196) {
        float o0 = 0.f, o1 = 0.f, pz = 0.f;
#pragma unroll
        for (int c4 = 0; c4 < 32; c4 += 4) {
          f4 qv = *(const f4*)(qp + n * 32 + c4);
#pragma unroll
          for (int j = 0; j < 4; ++j) {
            o0 += qv[j] * kv0[c4 + j];
            o1 += qv[j] * kv1[c4 + j];
            pz += qv[j] * ks[c4 + j];
          }
        }
        float z = 1.f / (pz + 1e-6f);
        u32 fmp = *(const u32*)(sfmb + n * 80 + dp * 4);
        float r0 = fmaf(o0, z, bflo(fmp));
        float r1 = fmaf(o1, z, bfhi(fmp));
        u32 u0 = __float_as_uint(r0), u1 = __float_as_uint(r1);
        u32 hpk = (u0 >> 16) | (u1 & 0xffff0000u);
        float l0 = r0 - __uint_as_float(u0 & 0xffff0000u);
        float l1 = r1 - __uint_as_float(u1 & 0xffff0000u);
        u32 lpk = cvt_pk_bf16(l0, l1);
        *(u32*)(yhp + n * 32 + d0) = hpk;
        *(u32*)(ylp + n * 32 + d0) = lpk;
      }
    }
  }
}

// ---------------- kernel 3m: out = y @ proj_w^T + proj_b ----------------
__global__ __launch_bounds__(256, 2) void proj_gemm(
    const u16* __restrict__ yh, const u16* __restrict__ yl,
    const u16* __restrict__ wh, const u16* __restrict__ wl,
    const float* __restrict__ bias, float* __restrict__ out)
{
  __shared__ __align__(16) char lds[2][32768];
  const int tid  = threadIdx.x;
  const int lane = tid & 63, wv = tid >> 6;
  const int L  = ((int)blockIdx.x & 7) * 588 + ((int)blockIdx.x >> 3);  // 4704 = 8*588
  const int rt = L / 3, ct = L - rt * 3;
  const int m0 = rt * 128, t0 = ct * 128;

  const int srow = tid >> 3;
  const int c8s  = (tid & 7) ^ (2 * ((tid >> 5) & 1));
  const int doff = (c8s & 3) * 8;
  const u16* sp[8];
#pragma unroll
  for (int jj = 0; jj < 4; ++jj) {
    int m = m0 + jj * 32 + srow;
    int b = m / 196, n = m - b * 196;
    const u16* basep = (c8s < 4) ? yh : yl;
    sp[jj] = basep + ((size_t)b * 12 * 196 + n) * 32 + doff;   // +kt*6272 per head
  }
#pragma unroll
  for (int jj = 4; jj < 8; ++jj) {
    const u16* basep = (c8s < 4) ? wh : wl;
    sp[jj] = basep + (size_t)(t0 + (jj - 4) * 32 + srow) * NC + doff;
  }

  auto stage = [&](char* buf) {
#pragma unroll
    for (int jj = 0; jj < 8; ++jj) {
      gload_lds16(sp[jj], buf + jj * 4096 + tid * 16);
      sp[jj] += (jj < 4) ? 6272 : 32;
    }
  };

  const int wm = (wv & 1) * 64, wn = (wv >> 1) * 64;
  const int l15 = lane & 15, l4 = lane >> 4;
  const int xb = 2 * ((l15 >> 2) & 1);
  int aoff[4], boff[4];
#pragma unroll
  for (int i = 0; i < 4; ++i) {
    int r = wm + i * 16 + l15;
    aoff[i] = r * 128 + ((l4 ^ xb) * 16);
    int t = wn + i * 16 + l15;
    boff[i] = t * 128 + ((l4 ^ xb) * 16);
  }

  f4 acc[4][4];
  const f4 fz = {0.f, 0.f, 0.f, 0.f};
#pragma unroll
  for (int i = 0; i < 4; ++i)
#pragma unroll
    for (int j = 0; j < 4; ++j) acc[i][j] = fz;

  stage(lds[0]);
  for (int kt = 0; kt < 12; ++kt) {
    __syncthreads();
    if (kt < 11) stage(lds[(kt + 1) & 1]);
    char* bufA = lds[kt & 1];
    char* bufB = bufA + 16384;
    bx8 ah[4], al[4], bh4[4], bl4[4];
#pragma unroll
    for (int i = 0; i < 4; ++i) {
      ah[i]  = *(const bx8*)(bufA + aoff[i]);
      al[i]  = *(const bx8*)(bufA + aoff[i] + 64);
      bh4[i] = *(const bx8*)(bufB + boff[i]);
      bl4[i] = *(const bx8*)(bufB + boff[i] + 64);
    }
#pragma unroll
    for (int mi = 0; mi < 4; ++mi)
#pragma unroll
      for (int ni = 0; ni < 4; ++ni) {
        acc[mi][ni] = __builtin_amdgcn_mfma_f32_16x16x32_bf16(ah[mi], bh4[ni], acc[mi][ni], 0, 0, 0);
        acc[mi][ni] = __builtin_amdgcn_mfma_f32_16x16x32_bf16(ah[mi], bl4[ni], acc[mi][ni], 0, 0, 0);
        acc[mi][ni] = __builtin_amdgcn_mfma_f32_16x16x32_bf16(al[mi], bh4[ni], acc[mi][ni], 0, 0, 0);
      }
  }

  float biasv[4];
#pragma unroll
  for (int ni = 0; ni < 4; ++ni) biasv[ni] = bias[t0 + wn + ni * 16 + l15];
#pragma unroll
  for (int mi = 0; mi < 4; ++mi) {
#pragma unroll
    for (int rr = 0; rr < 4; ++rr) {
      int m = m0 + wm + mi * 16 + l4 * 4 + rr;
      size_t ob = (size_t)m * 384 + t0 + wn;
#pragma unroll
      for (int ni = 0; ni < 4; ++ni)
        out[ob + ni * 16 + l15] = acc[mi][ni][rr] + biasv[ni];
    }
  }
}

// ================= FALLBACK PATH (round-2 kernels, verbatim) =================
__global__ __launch_bounds__(256, 2) void qkv_gemm_fb(
    const float* __restrict__ x, const u16* __restrict__ wh, const u16* __restrict__ wl,
    const float* __restrict__ bias, const float* __restrict__ pos,
    float* __restrict__ qo, float* __restrict__ ko, float* __restrict__ vo)
{
  __shared__ __align__(16) char lds[2][32768];
  const int tid  = threadIdx.x;
  const int lane = tid & 63, wv = tid >> 6;
  const int L  = ((int)blockIdx.x & 7) * 1764 + ((int)blockIdx.x >> 3);
  const int rt = L / 9, ct = L - rt * 9;
  const int m0 = rt * 128, t0 = ct * 128;

  const float* a_src[4];
  {
    int sg = lane & 7, lr = lane >> 3;
#pragma unroll
    for (int j = 0; j < 4; ++j) {
      int r = (wv * 4 + j) * 8 + lr;
      int g = sg ^ (r & 7);
      a_src[j] = x + (size_t)(m0 + r) * NC + g * 4;
    }
  }
  const u16 *bh_src[2], *bl_src[2];
#pragma unroll
  for (int j = 0; j < 2; ++j) {
    int gi = (wv * 2 + j) * 64 + lane;
    int kb = gi >> 7, t = gi & 127;
    size_t o = (size_t)(t0 + t) * NC + kb * 8;
    bh_src[j] = wh + o;
    bl_src[j] = wl + o;
  }

  auto stage = [&](char* buf, int k0) {
#pragma unroll
    for (int j = 0; j < 4; ++j)
      gload_lds16(a_src[j] + k0, buf + (wv * 4 + j) * 1024);
#pragma unroll
    for (int j = 0; j < 2; ++j) {
      gload_lds16(bh_src[j] + k0, buf + 16384 + (wv * 2 + j) * 1024);
      gload_lds16(bl_src[j] + k0, buf + 24576 + (wv * 2 + j) * 1024);
    }
  };

  const int wm = (wv & 1) * 64, wn = (wv >> 1) * 64;
  const int l15 = lane & 15, l4 = lane >> 4;
  int boff[4], aoff0[4], aoff1[4];
#pragma unroll
  for (int i = 0; i < 4; ++i) {
    boff[i] = (l4 * 128 + wn + i * 16 + l15) * 16;
    int r = wm + i * 16 + l15;
    aoff0[i] = r * 128 + (((l4 * 2)     ^ (r & 7)) * 16);
    aoff1[i] = r * 128 + (((l4 * 2 + 1) ^ (r & 7)) * 16);
  }

  f4 acc[4][4];
  const f4 fz = {0.f, 0.f, 0.f, 0.f};
#pragma unroll
  for (int i = 0; i < 4; ++i)
#pragma unroll
    for (int j = 0; j < 4; ++j) acc[i][j] = fz;

  stage(lds[0], 0);
  for (int kt = 0; kt < 12; ++kt) {
    __syncthreads();
    if (kt < 11) stage(lds[(kt + 1) & 1], (kt + 1) * 32);
    char* buf = lds[kt & 1];
    bx8 bhf[4], blf[4];
#pragma unroll
    for (int i = 0; i < 4; ++i) {
      bhf[i] = *(const bx8*)(buf + 16384 + boff[i]);
      blf[i] = *(const bx8*)(buf + 24576 + boff[i]);
    }
#pragma unroll
    for (int mi = 0; mi < 4; ++mi) {
      f4 fa = *(const f4*)(buf + aoff0[mi]);
      f4 fb = *(const f4*)(buf + aoff1[mi]);
      bx8 ah, al;
#pragma unroll
      for (int e = 0; e < 4; ++e) { short h, l; split_hi_lo(fa[e], h, l); ah[e] = h; al[e] = l; }
#pragma unroll
      for (int e = 0; e < 4; ++e) { short h, l; split_hi_lo(fb[e], h, l); ah[4+e] = h; al[4+e] = l; }
#pragma unroll
      for (int ni = 0; ni < 4; ++ni) {
        acc[mi][ni] = __builtin_amdgcn_mfma_f32_16x16x32_bf16(ah, bhf[ni], acc[mi][ni], 0, 0, 0);
        acc[mi][ni] = __builtin_amdgcn_mfma_f32_16x16x32_bf16(ah, blf[ni], acc[mi][ni], 0, 0, 0);
        acc[mi][ni] = __builtin_amdgcn_mfma_f32_16x16x32_bf16(al, bhf[ni], acc[mi][ni], 0, 0, 0);
      }
    }
  }

  const int s = ct / 3, cb = (ct - s * 3) * 128;
  float* outp = (s == 0) ? qo : ((s == 1) ? ko : vo);
  float biasv[4];
#pragma unroll
  for (int ni = 0; ni < 4; ++ni) biasv[ni] = bias[t0 + wn + ni * 16 + l15];
#pragma unroll
  for (int mi = 0; mi < 4; ++mi) {
#pragma unroll
    for (int rr = 0; rr < 4; ++rr) {
      int m = m0 + wm + mi * 16 + l4 * 4 + rr;
      int b = m / 196, n = m - b * 196;
      size_t rowb = (size_t)b * 75264 + (size_t)n * 32;
#pragma unroll
      for (int ni = 0; ni < 4; ++ni) {
        int c = cb + wn + ni * 16 + l15;
        float val = acc[mi][ni][rr] + biasv[ni];
        if (s == 0) val = fmaxf(val, 0.f);
        if (s == 1) { val += pos[n * 384 + c]; val = fmaxf(val, 0.f); }
        outp[rowb + (size_t)(c >> 5) * 6272 + (c & 31)] = val;
      }
    }
  }
}

__global__ __launch_bounds__(256, 4) void attn_conv_fb(
    const float* __restrict__ q, const float* __restrict__ k,
    const float* __restrict__ v, float* __restrict__ y,
    const float* __restrict__ dwc_w, const float* __restrict__ dwc_b)
{
  __shared__ __align__(16) u16  sv[NN * 40];
  __shared__ __align__(16) u16  sfm[NN * 40];
  __shared__ __align__(16) float skv[32 * 36];
  __shared__ float sksum[32];

  const int tid = threadIdx.x;
  const size_t base = (size_t)blockIdx.x * PH;
  const float* vp = v + base;
  const float* kp = k + base;
  const float* qp = q + base;
  float* yp = y + base;
  char* svb  = (char*)sv;
  char* sfmb = (char*)sfm;

  for (int c = tid; c < 784; c += 256) {
    f4 f0 = ((const f4*)vp)[c * 2];
    f4 f1 = ((const f4*)vp)[c * 2 + 1];
    u32x4 pk;
    pk[0] = cvt_pk_bf16(f0[0], f0[1]);
    pk[1] = cvt_pk_bf16(f0[2], f0[3]);
    pk[2] = cvt_pk_bf16(f1[0], f1[1]);
    pk[3] = cvt_pk_bf16(f1[2], f1[3]);
    *(u32x4*)(svb + (c >> 2) * 80 + (c & 3) * 16) = pk;
  }
  __syncthreads();

  {
    const int c = tid >> 3, ns = tid & 7;
    float acc[33];
#pragma unroll
    for (int d = 0; d < 33; ++d) acc[d] = 0.f;
    for (int i = 0; i < 25; ++i) {
      int n = i * 8 + ns;
      if (n < 196) {
        float kc = kp[n * 32 + c];
#pragma unroll
        for (int g = 0; g < 4; ++g) {
          u32x4 r = *(const u32x4*)(svb + n * 80 + g * 16);
#pragma unroll
          for (int j = 0; j < 4; ++j) {
            acc[g * 8 + 2 * j]     += kc * bflo(r[j]);
            acc[g * 8 + 2 * j + 1] += kc * bfhi(r[j]);
          }
        }
        acc[32] += kc;
      }
    }
#pragma unroll
    for (int off = 1; off <= 4; off <<= 1) {
#pragma unroll
      for (int d = 0; d < 33; ++d) acc[d] += __shfl_xor(acc[d], off);
    }
    if (ns == 0) {
#pragma unroll
      for (int d4 = 0; d4 < 32; d4 += 4) {
        f4 w; w[0] = acc[d4]; w[1] = acc[d4+1]; w[2] = acc[d4+2]; w[3] = acc[d4+3];
        *(f4*)&skv[c * 36 + d4] = w;
      }
      sksum[c] = acc[32];
    }
  }

  {
    const int dp = tid & 15, py = tid >> 4;
    if (py < 14) {
      const int d0 = 2 * dp;
      float fm0[14], fm1[14];
      const float b0 = dwc_b[d0], b1 = dwc_b[d0 + 1];
#pragma unroll
      for (int px = 0; px < 14; ++px) { fm0[px] = b0; fm1[px] = b1; }
#pragma unroll
      for (int ky = 0; ky < 5; ++ky) {
        int yy = py + ky - 2;
        if (yy < 0 || yy >= 14) continue;
        float w0[5], w1[5];
#pragma unroll
        for (int t = 0; t < 5; ++t) {
          w0[t] = dwc_w[d0 * 25 + ky * 5 + t];
          w1[t] = dwc_w[(d0 + 1) * 25 + ky * 5 + t];
        }
        float r0[14], r1[14];
#pragma unroll
        for (int xx = 0; xx < 14; ++xx) {
          u32 pr = *(const u32*)(svb + (yy * 14 + xx) * 80 + dp * 4);
          r0[xx] = bflo(pr); r1[xx] = bfhi(pr);
        }
#pragma unroll
        for (int px = 0; px < 14; ++px) {
#pragma unroll
          for (int kx = 0; kx < 5; ++kx) {
            int xx = px + kx - 2;
            if (xx < 0 || xx > 13) continue;
            fm0[px] += w0[kx] * r0[xx];
            fm1[px] += w1[kx] * r1[xx];
          }
        }
      }
#pragma unroll
      for (int px = 0; px < 14; ++px)
        *(u32*)(sfmb + (py * 14 + px) * 80 + dp * 4) = cvt_pk_bf16(fm0[px], fm1[px]);
    }
  }
  __syncthreads();

  {
    const int dp = tid & 15, ng = tid >> 4;
    const int d0 = 2 * dp;
    float kv0[32], kv1[32], ks[32];
#pragma unroll
    for (int c = 0; c < 32; ++c) {
      const float* p = &skv[c * 36 + d0];
      kv0[c] = p[0]; kv1[c] = p[1];
    }
#pragma unroll
    for (int c = 0; c < 32; ++c) ks[c] = sksum[c];
#pragma unroll 2
    for (int i = 0; i < 13; ++i) {
      int n = i * 16 + ng;
      if (n < 196) {
        float o0 = 0.f, o1 = 0.f, pz = 0.f;
#pragma unroll
        for (int c4 = 0; c4 < 32; c4 += 4) {
          f4 qv = *(const f4*)(qp + n * 32 + c4);
#pragma unroll
          for (int j = 0; j < 4; ++j) {
            o0 += qv[j] * kv0[c4 + j];
            o1 += qv[j] * kv1[c4 + j];
            pz += qv[j] * ks[c4 + j];
          }
        }
        float z = 1.f / (pz + 1e-6f);
        u32 fmp = *(const u32*)(sfmb + n * 80 + dp * 4);
        f2 r; r[0] = fmaf(o0, z, bflo(fmp)); r[1] = fmaf(o1, z, bfhi(fmp));
        *(f2*)(yp + n * 32 + d0) = r;
      }
    }
  }
}

__global__ __launch_bounds__(256, 2) void proj_gemm_fb(
    const float* __restrict__ yv, const u16* __restrict__ wh, const u16* __restrict__ wl,
    const float* __restrict__ bias, float* __restrict__ out)
{
  __shared__ __align__(16) char lds[2][32768];
  const int tid  = threadIdx.x;
  const int lane = tid & 63, wv = tid >> 6;
  const int L  = ((int)blockIdx.x & 7) * 588 + ((int)blockIdx.x >> 3);
  const int rt = L / 3, ct = L - rt * 3;
  const int m0 = rt * 128, t0 = ct * 128;

  u32 a_rowb[4]; int a_d[4];
  {
    int sg = lane & 7, lr = lane >> 3;
#pragma unroll
    for (int j = 0; j < 4; ++j) {
      int r = (wv * 4 + j) * 8 + lr;
      int m = m0 + r;
      int b = m / 196, n = m - b * 196;
      a_rowb[j] = (u32)b * 75264u + (u32)n * 32u;
      a_d[j] = (sg ^ (r & 7)) * 4;
    }
  }
  const u16 *bh_src[2], *bl_src[2];
#pragma unroll
  for (int j = 0; j < 2; ++j) {
    int gi = (wv * 2 + j) * 64 + lane;
    int kb = gi >> 7, t = gi & 127;
    size_t o = (size_t)(t0 + t) * NC + kb * 8;
    bh_src[j] = wh + o;
    bl_src[j] = wl + o;
  }

  auto stage = [&](char* buf, int kh) {
#pragma unroll
    for (int j = 0; j < 4; ++j)
      gload_lds16(yv + a_rowb[j] + (size_t)kh * 6272 + a_d[j], buf + (wv * 4 + j) * 1024);
#pragma unroll
    for (int j = 0; j < 2; ++j) {
      gload_lds16(bh_src[j] + kh * 32, buf + 16384 + (wv * 2 + j) * 1024);
      gload_lds16(bl_src[j] + kh * 32, buf + 24576 + (wv * 2 + j) * 1024);
    }
  };

  const int wm = (wv & 1) * 64, wn = (wv >> 1) * 64;
  const int l15 = lane & 15, l4 = lane >> 4;
  int boff[4], aoff0[4], aoff1[4];
#pragma unroll
  for (int i = 0; i < 4; ++i) {
    boff[i] = (l4 * 128 + wn + i * 16 + l15) * 16;
    int r = wm + i * 16 + l15;
    aoff0[i] = r * 128 + (((l4 * 2)     ^ (r & 7)) * 16);
    aoff1[i] = r * 128 + (((l4 * 2 + 1) ^ (r & 7)) * 16);
  }

  f4 acc[4][4];
  const f4 fz = {0.f, 0.f, 0.f, 0.f};
#pragma unroll
  for (int i = 0; i < 4; ++i)
#pragma unroll
    for (int j = 0; j < 4; ++j) acc[i][j] = fz;

  stage(lds[0], 0);
  for (int kt = 0; kt < 12; ++kt) {
    __syncthreads();
    if (kt < 11) stage(lds[(kt + 1) & 1], kt + 1);
    char* buf = lds[kt & 1];
    bx8 bhf[4], blf[4];
#pragma unroll
    for (int i = 0; i < 4; ++i) {
      bhf[i] = *(const bx8*)(buf + 16384 + boff[i]);
      blf[i] = *(const bx8*)(buf + 24576 + boff[i]);
    }
#pragma unroll
    for (int mi = 0; mi < 4; ++mi) {
      f4 fa = *(const f4*)(buf + aoff0[mi]);
      f4 fb = *(const f4*)(buf + aoff1[mi]);
      bx8 ah, al;
#pragma unroll
      for (int e = 0; e < 4; ++e) { short h, l; split_hi_lo(fa[e], h, l); ah[e] = h; al[e] = l; }
#pragma unroll
      for (int e = 0; e < 4; ++e) { short h, l; split_hi_lo(fb[e], h, l); ah[4+e] = h; al[4+e] = l; }
#pragma unroll
      for (int ni = 0; ni < 4; ++ni) {
        acc[mi][ni] = __builtin_amdgcn_mfma_f32_16x16x32_bf16(ah, bhf[ni], acc[mi][ni], 0, 0, 0);
        acc[mi][ni] = __builtin_amdgcn_mfma_f32_16x16x32_bf16(ah, blf[ni], acc[mi][ni], 0, 0, 0);
        acc[mi][ni] = __builtin_amdgcn_mfma_f32_16x16x32_bf16(al, bhf[ni], acc[mi][ni], 0, 0, 0);
      }
    }
  }

  float biasv[4];
#pragma unroll
  for (int ni = 0; ni < 4; ++ni) biasv[ni] = bias[t0 + wn + ni * 16 + l15];
#pragma unroll
  for (int mi = 0; mi < 4; ++mi) {
#pragma unroll
    for (int rr = 0; rr < 4; ++rr) {
      int m = m0 + wm + mi * 16 + l4 * 4 + rr;
      size_t ob = (size_t)m * 384 + t0 + wn;
#pragma unroll
      for (int ni = 0; ni < 4; ++ni)
        out[ob + ni * 16 + l15] = acc[mi][ni][rr] + biasv[ni];
    }
  }
}

// ---------------- launcher ----------------
extern "C" void kernel_launch(void* const* d_in, const int* in_sizes, int n_in,
                              void* d_out, int out_size, void* d_ws, size_t ws_size,
                              hipStream_t stream)
{
  const float* x      = (const float*)d_in[0];
  const float* qkv_w  = (const float*)d_in[1];
  const float* qkv_b  = (const float*)d_in[2];
  const float* proj_w = (const float*)d_in[3];
  const float* proj_b = (const float*)d_in[4];
  const float* dwc_w  = (const float*)d_in[5];
  const float* dwc_b  = (const float*)d_in[6];
  const float* pos    = (const float*)d_in[7];
  float* out = (float*)d_out;
  char* ws = (char*)d_ws;

  if (ws_size >= NEED_MAIN) {
    float* qb  = (float*)(ws + OFF_Q);
    float* kb  = (float*)(ws + OFF_K);
    u16*   vb  = (u16*)(ws + OFF_V);
    u16*   wqh = (u16*)(ws + OFF_WQH);
    u16*   wql = (u16*)(ws + OFF_WQL);
    u16*   wph = (u16*)(ws + OFF_WPH);
    u16*   wpl = (u16*)(ws + OFF_WPL);
    u16*   xh  = (u16*)(ws + OFF_XH);
    u16*   xl  = (u16*)(ws + OFF_XL);
    u16*   yh  = (u16*)(ws + OFF_K);   // overlays k (safe: k consumed in-phase)
    u16*   yl  = (u16*)(ws + OFF_V);   // overlays v (safe: v consumed in-phase)

    split_weights<<<1728, 256, 0, stream>>>(qkv_w, proj_w, wqh, wql, wph, wpl);
    split_x<<<37632, 256, 0, stream>>>(x, xh, xl);
    qkv_gemm<<<14112, 256, 0, stream>>>(xh, xl, wqh, wql, qkv_b, pos, qb, kb, vb);
    attn_conv<<<12288, 256, 0, stream>>>(qb, kb, vb, yh, yl, dwc_w, dwc_b);
    proj_gemm<<<4704, 256, 0, stream>>>(yh, yl, wph, wpl, proj_b, out);
  } else {
    float* qb  = (float*)(ws + OFF_Q_FB);
    float* kb  = (float*)(ws + OFF_K_FB);
    float* vb  = (float*)(ws + OFF_V_FB);
    u16*   wqh = (u16*)(ws + OFF_WQH_FB);
    u16*   wql = (u16*)(ws + OFF_WQL_FB);
    u16*   wph = (u16*)(ws + OFF_WPH_FB);
    u16*   wpl = (u16*)(ws + OFF_WPL_FB);

    split_weights<<<1728, 256, 0, stream>>>(qkv_w, proj_w, wqh, wql, wph, wpl);
    qkv_gemm_fb<<<14112, 256, 0, stream>>>(x, wqh, wql, qkv_b, pos, qb, kb, vb);
    attn_conv_fb<<<12288, 256, 0, stream>>>(qb, kb, vb, vb, dwc_w, dwc_b);
    proj_gemm_fb<<<4704, 256, 0, stream>>>(vb, wph, wpl, proj_b, out);
  }
}

// Round 4
// 1508.436 us; speedup vs baseline: 1.5842x; 1.0121x over previous
//
#include <hip/hip_runtime.h>
#include <cstdint>

#define DI __device__ __forceinline__

typedef __attribute__((ext_vector_type(8))) short bx8;   // 8 x bf16 (bit pattern)
typedef __attribute__((ext_vector_type(4))) float f4;
typedef __attribute__((ext_vector_type(2))) float f2;
typedef unsigned short u16;
typedef unsigned int u32;
typedef __attribute__((ext_vector_type(4))) u32 u32x4;

// ---------------- problem constants ----------------
constexpr int NB = 1024;         // batch
constexpr int NN = 196;          // tokens
constexpr int NC = 384;          // channels
constexpr int NH = 12;           // heads
constexpr int HD = 32;           // head dim
constexpr int C3 = 3 * NC;       // 1152
constexpr int PH = NN * HD;      // 6272 elements per (b,h)

// ======== main-path workspace layout (bytes) ========
constexpr size_t SZ_T    = (size_t)NB * NH * PH * 4;   // 308,281,344 (fp32 tensor)
constexpr size_t SZ_TH   = SZ_T / 2;                   // 154,140,672 (u16 tensor)
constexpr size_t OFF_Q   = 0;                          // q fp32
constexpr size_t OFF_K   = SZ_T;                       // k fp32 ; yh u16 overlays
constexpr size_t OFF_V   = 2 * SZ_T;                   // v bf16 ; yl u16 overlays
constexpr size_t OFF_WQH = OFF_V + SZ_TH;              // 770,703,360
constexpr size_t SZ_WQ   = (size_t)C3 * NC * 2;        // 884,736
constexpr size_t OFF_WQL = OFF_WQH + SZ_WQ;
constexpr size_t OFF_WPH = OFF_WQL + SZ_WQ;
constexpr size_t SZ_WP   = (size_t)NC * NC * 2;        // 294,912
constexpr size_t OFF_WPL = OFF_WPH + SZ_WP;
constexpr size_t OFF_XH  = OFF_WPL + SZ_WP;            // 773,062,656
constexpr size_t OFF_XL  = OFF_XH + SZ_TH;
constexpr size_t NEED_MAIN = OFF_XL + SZ_TH;           // 1,081,344,000

// ======== fallback (round-2) workspace layout ========
constexpr size_t OFF_Q_FB   = 0;
constexpr size_t OFF_K_FB   = SZ_T;
constexpr size_t OFF_V_FB   = 2 * SZ_T;
constexpr size_t OFF_WQH_FB = 3 * SZ_T;
constexpr size_t OFF_WQL_FB = OFF_WQH_FB + SZ_WQ;
constexpr size_t OFF_WPH_FB = OFF_WQL_FB + SZ_WQ;
constexpr size_t OFF_WPL_FB = OFF_WPH_FB + SZ_WP;

DI void gload_lds16(const void* g, void* l) {
  using GP = const void __attribute__((address_space(1)))*;
  using LP = void __attribute__((address_space(3)))*;
  __builtin_amdgcn_global_load_lds((GP)g, (LP)l, 16, 0, 0);
}

DI void split_hi_lo(float f, short& hi, short& lo) {
  u32 u = __float_as_uint(f);
  hi = (short)(u >> 16);
  float l = f - __uint_as_float(u & 0xffff0000u);   // exact
  lo = (short)(__float_as_uint(l) >> 16);
}

DI u32 cvt_pk_bf16(float lo, float hi) {   // dst = bf16(lo) | bf16(hi)<<16, RNE
  u32 r;
  asm volatile("v_cvt_pk_bf16_f32 %0, %1, %2" : "=v"(r) : "v"(lo), "v"(hi));
  return r;
}
DI float bflo(u32 p) { return __uint_as_float(p << 16); }
DI float bfhi(u32 p) { return __uint_as_float(p & 0xffff0000u); }

// ---------------- kernel: pre-split weight matrices (both paths) ----------------
__global__ void split_weights(const float* __restrict__ qw, const float* __restrict__ pw,
                              u16* __restrict__ qh, u16* __restrict__ ql,
                              u16* __restrict__ ph, u16* __restrict__ pl)
{
  int i = blockIdx.x * 256 + threadIdx.x;
  if (i < C3 * NC) {
    float f = qw[i];
    u32 u = __float_as_uint(f);
    qh[i] = (u16)(u >> 16);
    float lo = f - __uint_as_float(u & 0xffff0000u);
    u32 ul = __float_as_uint(lo);
    ul += 0x7fffu + ((ul >> 16) & 1u);               // RNE on residual
    ql[i] = (u16)(ul >> 16);
  }
  if (i < NC * NC) {
    float f = pw[i];
    u32 u = __float_as_uint(f);
    ph[i] = (u16)(u >> 16);
    float lo = f - __uint_as_float(u & 0xffff0000u);
    u32 ul = __float_as_uint(lo);
    ul += 0x7fffu + ((ul >> 16) & 1u);
    pl[i] = (u16)(ul >> 16);
  }
}

// ---------------- kernel: pre-split x into bf16 hi/lo ----------------
__global__ void split_x(const float* __restrict__ x, u16* __restrict__ xh, u16* __restrict__ xl)
{
  size_t i = ((size_t)blockIdx.x * 256 + threadIdx.x) * 8;
  f4 a = *(const f4*)(x + i);
  f4 b = *(const f4*)(x + i + 4);
  float v[8] = {a[0], a[1], a[2], a[3], b[0], b[1], b[2], b[3]};
  u32x4 hp, lp;
#pragma unroll
  for (int j = 0; j < 4; ++j) {
    float v0 = v[2 * j], v1 = v[2 * j + 1];
    u32 u0 = __float_as_uint(v0), u1 = __float_as_uint(v1);
    hp[j] = (u0 >> 16) | (u1 & 0xffff0000u);
    float l0 = v0 - __uint_as_float(u0 & 0xffff0000u);
    float l1 = v1 - __uint_as_float(u1 & 0xffff0000u);
    lp[j] = cvt_pk_bf16(l0, l1);
  }
  *(u32x4*)(xh + i) = hp;
  *(u32x4*)(xl + i) = lp;
}

// ================= MAIN PATH =================
// GEMM tiles: [128 rows][128B]; column-granule c (16B, c<4 = hi k-granule, c>=4 = lo)
// stored at slot s = c ^ (r&7)  -> full 3-bit XOR: bank index spans all 32 banks,
// uniform 8 dword-accesses/bank per b128 wave read (the wave64 minimum).
// Linear LDS dest via global_load_lds; inverse permutation on per-lane GLOBAL source.

// ---------------- kernel 1m: qkv = x @ qkv_w^T + b ; relu/pos ; head-split ----------------
__global__ __launch_bounds__(256, 2) void qkv_gemm(
    const u16* __restrict__ xh, const u16* __restrict__ xl,
    const u16* __restrict__ wh, const u16* __restrict__ wl,
    const float* __restrict__ bias, const float* __restrict__ pos,
    float* __restrict__ qo, float* __restrict__ ko, u16* __restrict__ vo)
{
  __shared__ __align__(16) char lds[2][32768];   // A 16K | B 16K
  const int tid  = threadIdx.x;
  const int lane = tid & 63, wv = tid >> 6;
  const int L  = ((int)blockIdx.x & 7) * 1764 + ((int)blockIdx.x >> 3); // 14112 = 8*1764
  const int rt = L / 9, ct = L - rt * 9;
  const int m0 = rt * 128, t0 = ct * 128;

  // staging: LDS slot s = tid&7 of row srow holds column-granule c8s = s ^ (srow&7)
  const int srow = tid >> 3;
  const int c8s  = (tid & 7) ^ (srow & 7);
  const int doff = (c8s & 3) * 8;
  const u16* sp[8];
#pragma unroll
  for (int jj = 0; jj < 4; ++jj) {
    const u16* basep = (c8s < 4) ? xh : xl;
    sp[jj] = basep + (size_t)(m0 + jj * 32 + srow) * NC + doff;
  }
#pragma unroll
  for (int jj = 4; jj < 8; ++jj) {
    const u16* basep = (c8s < 4) ? wh : wl;
    sp[jj] = basep + (size_t)(t0 + (jj - 4) * 32 + srow) * NC + doff;
  }

  auto stage = [&](char* buf) {
#pragma unroll
    for (int jj = 0; jj < 8; ++jj) {
      gload_lds16(sp[jj], buf + jj * 4096 + tid * 16);
      sp[jj] += 32;                                   // next K-step (32 u16)
    }
  };

  const int wm = (wv & 1) * 64, wn = (wv >> 1) * 64;
  const int l15 = lane & 15, l4 = lane >> 4;
  const int sl = l4 ^ (l15 & 7);                      // swizzled slot of hi granule l4
  int aoff[4], boff[4];
#pragma unroll
  for (int i = 0; i < 4; ++i) {
    aoff[i] = (wm + i * 16 + l15) * 128 + sl * 16;
    boff[i] = (wn + i * 16 + l15) * 128 + sl * 16;
  }

  f4 acc[4][4];
  const f4 fz = {0.f, 0.f, 0.f, 0.f};
#pragma unroll
  for (int i = 0; i < 4; ++i)
#pragma unroll
    for (int j = 0; j < 4; ++j) acc[i][j] = fz;

  stage(lds[0]);
  for (int kt = 0; kt < 12; ++kt) {
    __syncthreads();
    if (kt < 11) stage(lds[(kt + 1) & 1]);
    char* bufA = lds[kt & 1];
    char* bufB = bufA + 16384;
    bx8 ah[4], al[4], bh4[4], bl4[4];
#pragma unroll
    for (int i = 0; i < 4; ++i) {
      ah[i]  = *(const bx8*)(bufA + aoff[i]);
      al[i]  = *(const bx8*)(bufA + (aoff[i] ^ 64));  // lo slot = hi slot ^ 4
      bh4[i] = *(const bx8*)(bufB + boff[i]);
      bl4[i] = *(const bx8*)(bufB + (boff[i] ^ 64));
    }
#pragma unroll
    for (int mi = 0; mi < 4; ++mi)
#pragma unroll
      for (int ni = 0; ni < 4; ++ni) {
        acc[mi][ni] = __builtin_amdgcn_mfma_f32_16x16x32_bf16(ah[mi], bh4[ni], acc[mi][ni], 0, 0, 0);
        acc[mi][ni] = __builtin_amdgcn_mfma_f32_16x16x32_bf16(ah[mi], bl4[ni], acc[mi][ni], 0, 0, 0);
        acc[mi][ni] = __builtin_amdgcn_mfma_f32_16x16x32_bf16(al[mi], bh4[ni], acc[mi][ni], 0, 0, 0);
      }
  }

  // epilogue: bias, relu (q), pos+relu (k), bf16-RNE (v); head-split scatter
  const int s = ct / 3, cb = (ct - s * 3) * 128;   // s: 0=q 1=k 2=v
  float biasv[4];
#pragma unroll
  for (int ni = 0; ni < 4; ++ni) biasv[ni] = bias[t0 + wn + ni * 16 + l15];
#pragma unroll
  for (int mi = 0; mi < 4; ++mi) {
#pragma unroll
    for (int rr = 0; rr < 4; ++rr) {
      int m = m0 + wm + mi * 16 + l4 * 4 + rr;
      int b = m / 196, n = m - b * 196;
      size_t rowb = (size_t)b * 75264 + (size_t)n * 32;
#pragma unroll
      for (int ni = 0; ni < 4; ++ni) {
        int c = cb + wn + ni * 16 + l15;
        float val = acc[mi][ni][rr] + biasv[ni];
        size_t idx = rowb + (size_t)(c >> 5) * 6272 + (c & 31);
        if (s == 0) { qo[idx] = fmaxf(val, 0.f); }
        else if (s == 1) { ko[idx] = fmaxf(val + pos[n * 384 + c], 0.f); }
        else { vo[idx] = (u16)cvt_pk_bf16(val, val); }   // RNE bf16
      }
    }
  }
}

// ---------------- kernel 2m: per-(b,h) linear attention + depthwise conv ----------------
__global__ __launch_bounds__(256, 4) void attn_conv(
    const float* __restrict__ q, const float* k,
    const u16* v16, u16* yh, u16* yl,
    const float* __restrict__ dwc_w, const float* __restrict__ dwc_b)
{
  __shared__ __align__(16) u16  sv[NN * 40];    // bf16 v, rows padded to 40 (80B)
  __shared__ __align__(16) u16  sfm[NN * 40];   // bf16 conv output
  __shared__ __align__(16) float skv[32 * 36];  // kv fp32, row pad 36
  __shared__ float sksum[32];

  const int tid = threadIdx.x;
  const size_t base = (size_t)blockIdx.x * PH;
  const u16*   vp = v16 + base;
  const float* kp = k + base;
  const float* qp = q + base;
  u16* yhp = yh + base;
  u16* ylp = yl + base;
  char* svb  = (char*)sv;
  char* sfmb = (char*)sfm;

  // ---- phase 1: stage v bf16 -> padded LDS ----
  for (int c = tid; c < 784; c += 256) {        // 784 chunks of 16B (8 d's)
    u32x4 pk = *(const u32x4*)(vp + c * 8);
    *(u32x4*)(svb + (c >> 2) * 80 + (c & 3) * 16) = pk;
  }
  __syncthreads();

  // ---- phase 2: kv[c][d] = sum_n k[n][c]*v[n][d]  (8-way n-split + butterfly) ----
  {
    const int c = tid >> 3, ns = tid & 7;
    float acc[33];
#pragma unroll
    for (int d = 0; d < 33; ++d) acc[d] = 0.f;
    for (int i = 0; i < 25; ++i) {
      int n = i * 8 + ns;
      if (n < 196) {
        float kc = kp[n * 32 + c];
#pragma unroll
        for (int g = 0; g < 4; ++g) {
          u32x4 r = *(const u32x4*)(svb + n * 80 + g * 16);
#pragma unroll
          for (int j = 0; j < 4; ++j) {
            acc[g * 8 + 2 * j]     += kc * bflo(r[j]);
            acc[g * 8 + 2 * j + 1] += kc * bfhi(r[j]);
          }
        }
        acc[32] += kc;
      }
    }
#pragma unroll
    for (int off = 1; off <= 4; off <<= 1) {
#pragma unroll
      for (int d = 0; d < 33; ++d) acc[d] += __shfl_xor(acc[d], off);
    }
    if (ns == 0) {
#pragma unroll
      for (int d4 = 0; d4 < 32; d4 += 4) {
        f4 w; w[0] = acc[d4]; w[1] = acc[d4+1]; w[2] = acc[d4+2]; w[3] = acc[d4+3];
        *(f4*)&skv[c * 36 + d4] = w;
      }
      sksum[c] = acc[32];
    }
  }

  // ---- phase 3: depthwise 5x5 conv on v (d-pair threads), fm -> bf16 LDS ----
  {
    const int dp = tid & 15, py = tid >> 4;
    if (py < 14) {
      const int d0 = 2 * dp;
      float fm0[14], fm1[14];
      const float b0 = dwc_b[d0], b1 = dwc_b[d0 + 1];
#pragma unroll
      for (int px = 0; px < 14; ++px) { fm0[px] = b0; fm1[px] = b1; }
#pragma unroll
      for (int ky = 0; ky < 5; ++ky) {
        int yy = py + ky - 2;
        if (yy < 0 || yy >= 14) continue;
        float w0[5], w1[5];
#pragma unroll
        for (int t = 0; t < 5; ++t) {
          w0[t] = dwc_w[d0 * 25 + ky * 5 + t];
          w1[t] = dwc_w[(d0 + 1) * 25 + ky * 5 + t];
        }
        float r0[14], r1[14];
#pragma unroll
        for (int xx = 0; xx < 14; ++xx) {
          u32 pr = *(const u32*)(svb + (yy * 14 + xx) * 80 + dp * 4);
          r0[xx] = bflo(pr); r1[xx] = bfhi(pr);
        }
#pragma unroll
        for (int px = 0; px < 14; ++px) {
#pragma unroll
          for (int kx = 0; kx < 5; ++kx) {
            int xx = px + kx - 2;
            if (xx < 0 || xx > 13) continue;
            fm0[px] += w0[kx] * r0[xx];
            fm1[px] += w1[kx] * r1[xx];
          }
        }
      }
#pragma unroll
      for (int px = 0; px < 14; ++px)
        *(u32*)(sfmb + (py * 14 + px) * 80 + dp * 4) = cvt_pk_bf16(fm0[px], fm1[px]);
    }
  }
  __syncthreads();

  // ---- phase 4: y = z*(q@kv) + fm ; write split yh/yl ----
  {
    const int dp = tid & 15, ng = tid >> 4;
    const int d0 = 2 * dp;
    float kv0[32], kv1[32], ks[32];
#pragma unroll
    for (int c = 0; c < 32; ++c) {
      const float* p = &skv[c * 36 + d0];
      kv0[c] = p[0]; kv1[c] = p[1];
    }
#pragma unroll
    for (int c = 0; c < 32; ++c) ks[c] = sksum[c];
#pragma unroll 2
    for (int i = 0; i < 13; ++i) {
      int n = i * 16 + ng;
      if (n < 196) {
        float o0 = 0.f, o1 = 0.f, pz = 0.f;
#pragma unroll
        for (int c4 = 0; c4 < 32; c4 += 4) {
          f4 qv = *(const f4*)(qp + n * 32 + c4);
#pragma unroll
          for (int j = 0; j < 4; ++j) {
            o0 += qv[j] * kv0[c4 + j];
            o1 += qv[j] * kv1[c4 + j];
            pz += qv[j] * ks[c4 + j];
          }
        }
        float z = 1.f / (pz + 1e-6f);
        u32 fmp = *(const u32*)(sfmb + n * 80 + dp * 4);
        float r0 = fmaf(o0, z, bflo(fmp));
        float r1 = fmaf(o1, z, bfhi(fmp));
        u32 u0 = __float_as_uint(r0), u1 = __float_as_uint(r1);
        u32 hpk = (u0 >> 16) | (u1 & 0xffff0000u);
        float l0 = r0 - __uint_as_float(u0 & 0xffff0000u);
        float l1 = r1 - __uint_as_float(u1 & 0xffff0000u);
        u32 lpk = cvt_pk_bf16(l0, l1);
        *(u32*)(yhp + n * 32 + d0) = hpk;
        *(u32*)(ylp + n * 32 + d0) = lpk;
      }
    }
  }
}

// ---------------- kernel 3m: out = y @ proj_w^T + proj_b ----------------
__global__ __launch_bounds__(256, 2) void proj_gemm(
    const u16* __restrict__ yh, const u16* __restrict__ yl,
    const u16* __restrict__ wh, const u16* __restrict__ wl,
    const float* __restrict__ bias, float* __restrict__ out)
{
  __shared__ __align__(16) char lds[2][32768];
  const int tid  = threadIdx.x;
  const int lane = tid & 63, wv = tid >> 6;
  const int L  = ((int)blockIdx.x & 7) * 588 + ((int)blockIdx.x >> 3);  // 4704 = 8*588
  const int rt = L / 3, ct = L - rt * 3;
  const int m0 = rt * 128, t0 = ct * 128;

  const int srow = tid >> 3;
  const int c8s  = (tid & 7) ^ (srow & 7);
  const int doff = (c8s & 3) * 8;
  const u16* sp[8];
#pragma unroll
  for (int jj = 0; jj < 4; ++jj) {
    int m = m0 + jj * 32 + srow;
    int b = m / 196, n = m - b * 196;
    const u16* basep = (c8s < 4) ? yh : yl;
    sp[jj] = basep + ((size_t)b * 12 * 196 + n) * 32 + doff;   // +kt*6272 per head
  }
#pragma unroll
  for (int jj = 4; jj < 8; ++jj) {
    const u16* basep = (c8s < 4) ? wh : wl;
    sp[jj] = basep + (size_t)(t0 + (jj - 4) * 32 + srow) * NC + doff;
  }

  auto stage = [&](char* buf) {
#pragma unroll
    for (int jj = 0; jj < 8; ++jj) {
      gload_lds16(sp[jj], buf + jj * 4096 + tid * 16);
      sp[jj] += (jj < 4) ? 6272 : 32;
    }
  };

  const int wm = (wv & 1) * 64, wn = (wv >> 1) * 64;
  const int l15 = lane & 15, l4 = lane >> 4;
  const int sl = l4 ^ (l15 & 7);
  int aoff[4], boff[4];
#pragma unroll
  for (int i = 0; i < 4; ++i) {
    aoff[i] = (wm + i * 16 + l15) * 128 + sl * 16;
    boff[i] = (wn + i * 16 + l15) * 128 + sl * 16;
  }

  f4 acc[4][4];
  const f4 fz = {0.f, 0.f, 0.f, 0.f};
#pragma unroll
  for (int i = 0; i < 4; ++i)
#pragma unroll
    for (int j = 0; j < 4; ++j) acc[i][j] = fz;

  stage(lds[0]);
  for (int kt = 0; kt < 12; ++kt) {
    __syncthreads();
    if (kt < 11) stage(lds[(kt + 1) & 1]);
    char* bufA = lds[kt & 1];
    char* bufB = bufA + 16384;
    bx8 ah[4], al[4], bh4[4], bl4[4];
#pragma unroll
    for (int i = 0; i < 4; ++i) {
      ah[i]  = *(const bx8*)(bufA + aoff[i]);
      al[i]  = *(const bx8*)(bufA + (aoff[i] ^ 64));
      bh4[i] = *(const bx8*)(bufB + boff[i]);
      bl4[i] = *(const bx8*)(bufB + (boff[i] ^ 64));
    }
#pragma unroll
    for (int mi = 0; mi < 4; ++mi)
#pragma unroll
      for (int ni = 0; ni < 4; ++ni) {
        acc[mi][ni] = __builtin_amdgcn_mfma_f32_16x16x32_bf16(ah[mi], bh4[ni], acc[mi][ni], 0, 0, 0);
        acc[mi][ni] = __builtin_amdgcn_mfma_f32_16x16x32_bf16(ah[mi], bl4[ni], acc[mi][ni], 0, 0, 0);
        acc[mi][ni] = __builtin_amdgcn_mfma_f32_16x16x32_bf16(al[mi], bh4[ni], acc[mi][ni], 0, 0, 0);
      }
  }

  float biasv[4];
#pragma unroll
  for (int ni = 0; ni < 4; ++ni) biasv[ni] = bias[t0 + wn + ni * 16 + l15];
#pragma unroll
  for (int mi = 0; mi < 4; ++mi) {
#pragma unroll
    for (int rr = 0; rr < 4; ++rr) {
      int m = m0 + wm + mi * 16 + l4 * 4 + rr;
      size_t ob = (size_t)m * 384 + t0 + wn;
#pragma unroll
      for (int ni = 0; ni < 4; ++ni)
        out[ob + ni * 16 + l15] = acc[mi][ni][rr] + biasv[ni];
    }
  }
}

// ================= FALLBACK PATH (round-2 kernels, verbatim) =================
__global__ __launch_bounds__(256, 2) void qkv_gemm_fb(
    const float* __restrict__ x, const u16* __restrict__ wh, const u16* __restrict__ wl,
    const float* __restrict__ bias, const float* __restrict__ pos,
    float* __restrict__ qo, float* __restrict__ ko, float* __restrict__ vo)
{
  __shared__ __align__(16) char lds[2][32768];
  const int tid  = threadIdx.x;
  const int lane = tid & 63, wv = tid >> 6;
  const int L  = ((int)blockIdx.x & 7) * 1764 + ((int)blockIdx.x >> 3);
  const int rt = L / 9, ct = L - rt * 9;
  const int m0 = rt * 128, t0 = ct * 128;

  const float* a_src[4];
  {
    int sg = lane & 7, lr = lane >> 3;
#pragma unroll
    for (int j = 0; j < 4; ++j) {
      int r = (wv * 4 + j) * 8 + lr;
      int g = sg ^ (r & 7);
      a_src[j] = x + (size_t)(m0 + r) * NC + g * 4;
    }
  }
  const u16 *bh_src[2], *bl_src[2];
#pragma unroll
  for (int j = 0; j < 2; ++j) {
    int gi = (wv * 2 + j) * 64 + lane;
    int kb = gi >> 7, t = gi & 127;
    size_t o = (size_t)(t0 + t) * NC + kb * 8;
    bh_src[j] = wh + o;
    bl_src[j] = wl + o;
  }

  auto stage = [&](char* buf, int k0) {
#pragma unroll
    for (int j = 0; j < 4; ++j)
      gload_lds16(a_src[j] + k0, buf + (wv * 4 + j) * 1024);
#pragma unroll
    for (int j = 0; j < 2; ++j) {
      gload_lds16(bh_src[j] + k0, buf + 16384 + (wv * 2 + j) * 1024);
      gload_lds16(bl_src[j] + k0, buf + 24576 + (wv * 2 + j) * 1024);
    }
  };

  const int wm = (wv & 1) * 64, wn = (wv >> 1) * 64;
  const int l15 = lane & 15, l4 = lane >> 4;
  int boff[4], aoff0[4], aoff1[4];
#pragma unroll
  for (int i = 0; i < 4; ++i) {
    boff[i] = (l4 * 128 + wn + i * 16 + l15) * 16;
    int r = wm + i * 16 + l15;
    aoff0[i] = r * 128 + (((l4 * 2)     ^ (r & 7)) * 16);
    aoff1[i] = r * 128 + (((l4 * 2 + 1) ^ (r & 7)) * 16);
  }

  f4 acc[4][4];
  const f4 fz = {0.f, 0.f, 0.f, 0.f};
#pragma unroll
  for (int i = 0; i < 4; ++i)
#pragma unroll
    for (int j = 0; j < 4; ++j) acc[i][j] = fz;

  stage(lds[0], 0);
  for (int kt = 0; kt < 12; ++kt) {
    __syncthreads();
    if (kt < 11) stage(lds[(kt + 1) & 1], (kt + 1) * 32);
    char* buf = lds[kt & 1];
    bx8 bhf[4], blf[4];
#pragma unroll
    for (int i = 0; i < 4; ++i) {
      bhf[i] = *(const bx8*)(buf + 16384 + boff[i]);
      blf[i] = *(const bx8*)(buf + 24576 + boff[i]);
    }
#pragma unroll
    for (int mi = 0; mi < 4; ++mi) {
      f4 fa = *(const f4*)(buf + aoff0[mi]);
      f4 fb = *(const f4*)(buf + aoff1[mi]);
      bx8 ah, al;
#pragma unroll
      for (int e = 0; e < 4; ++e) { short h, l; split_hi_lo(fa[e], h, l); ah[e] = h; al[e] = l; }
#pragma unroll
      for (int e = 0; e < 4; ++e) { short h, l; split_hi_lo(fb[e], h, l); ah[4+e] = h; al[4+e] = l; }
#pragma unroll
      for (int ni = 0; ni < 4; ++ni) {
        acc[mi][ni] = __builtin_amdgcn_mfma_f32_16x16x32_bf16(ah, bhf[ni], acc[mi][ni], 0, 0, 0);
        acc[mi][ni] = __builtin_amdgcn_mfma_f32_16x16x32_bf16(ah, blf[ni], acc[mi][ni], 0, 0, 0);
        acc[mi][ni] = __builtin_amdgcn_mfma_f32_16x16x32_bf16(al, bhf[ni], acc[mi][ni], 0, 0, 0);
      }
    }
  }

  const int s = ct / 3, cb = (ct - s * 3) * 128;
  float* outp = (s == 0) ? qo : ((s == 1) ? ko : vo);
  float biasv[4];
#pragma unroll
  for (int ni = 0; ni < 4; ++ni) biasv[ni] = bias[t0 + wn + ni * 16 + l15];
#pragma unroll
  for (int mi = 0; mi < 4; ++mi) {
#pragma unroll
    for (int rr = 0; rr < 4; ++rr) {
      int m = m0 + wm + mi * 16 + l4 * 4 + rr;
      int b = m / 196, n = m - b * 196;
      size_t rowb = (size_t)b * 75264 + (size_t)n * 32;
#pragma unroll
      for (int ni = 0; ni < 4; ++ni) {
        int c = cb + wn + ni * 16 + l15;
        float val = acc[mi][ni][rr] + biasv[ni];
        if (s == 0) val = fmaxf(val, 0.f);
        if (s == 1) { val += pos[n * 384 + c]; val = fmaxf(val, 0.f); }
        outp[rowb + (size_t)(c >> 5) * 6272 + (c & 31)] = val;
      }
    }
  }
}

__global__ __launch_bounds__(256, 4) void attn_conv_fb(
    const float* __restrict__ q, const float* __restrict__ k,
    const float* __restrict__ v, float* __restrict__ y,
    const float* __restrict__ dwc_w, const float* __restrict__ dwc_b)
{
  __shared__ __align__(16) u16  sv[NN * 40];
  __shared__ __align__(16) u16  sfm[NN * 40];
  __shared__ __align__(16) float skv[32 * 36];
  __shared__ float sksum[32];

  const int tid = threadIdx.x;
  const size_t base = (size_t)blockIdx.x * PH;
  const float* vp = v + base;
  const float* kp = k + base;
  const float* qp = q + base;
  float* yp = y + base;
  char* svb  = (char*)sv;
  char* sfmb = (char*)sfm;

  for (int c = tid; c < 784; c += 256) {
    f4 f0 = ((const f4*)vp)[c * 2];
    f4 f1 = ((const f4*)vp)[c * 2 + 1];
    u32x4 pk;
    pk[0] = cvt_pk_bf16(f0[0], f0[1]);
    pk[1] = cvt_pk_bf16(f0[2], f0[3]);
    pk[2] = cvt_pk_bf16(f1[0], f1[1]);
    pk[3] = cvt_pk_bf16(f1[2], f1[3]);
    *(u32x4*)(svb + (c >> 2) * 80 + (c & 3) * 16) = pk;
  }
  __syncthreads();

  {
    const int c = tid >> 3, ns = tid & 7;
    float acc[33];
#pragma unroll
    for (int d = 0; d < 33; ++d) acc[d] = 0.f;
    for (int i = 0; i < 25; ++i) {
      int n = i * 8 + ns;
      if (n < 196) {
        float kc = kp[n * 32 + c];
#pragma unroll
        for (int g = 0; g < 4; ++g) {
          u32x4 r = *(const u32x4*)(svb + n * 80 + g * 16);
#pragma unroll
          for (int j = 0; j < 4; ++j) {
            acc[g * 8 + 2 * j]     += kc * bflo(r[j]);
            acc[g * 8 + 2 * j + 1] += kc * bfhi(r[j]);
          }
        }
        acc[32] += kc;
      }
    }
#pragma unroll
    for (int off = 1; off <= 4; off <<= 1) {
#pragma unroll
      for (int d = 0; d < 33; ++d) acc[d] += __shfl_xor(acc[d], off);
    }
    if (ns == 0) {
#pragma unroll
      for (int d4 = 0; d4 < 32; d4 += 4) {
        f4 w; w[0] = acc[d4]; w[1] = acc[d4+1]; w[2] = acc[d4+2]; w[3] = acc[d4+3];
        *(f4*)&skv[c * 36 + d4] = w;
      }
      sksum[c] = acc[32];
    }
  }

  {
    const int dp = tid & 15, py = tid >> 4;
    if (py < 14) {
      const int d0 = 2 * dp;
      float fm0[14], fm1[14];
      const float b0 = dwc_b[d0], b1 = dwc_b[d0 + 1];
#pragma unroll
      for (int px = 0; px < 14; ++px) { fm0[px] = b0; fm1[px] = b1; }
#pragma unroll
      for (int ky = 0; ky < 5; ++ky) {
        int yy = py + ky - 2;
        if (yy < 0 || yy >= 14) continue;
        float w0[5], w1[5];
#pragma unroll
        for (int t = 0; t < 5; ++t) {
          w0[t] = dwc_w[d0 * 25 + ky * 5 + t];
          w1[t] = dwc_w[(d0 + 1) * 25 + ky * 5 + t];
        }
        float r0[14], r1[14];
#pragma unroll
        for (int xx = 0; xx < 14; ++xx) {
          u32 pr = *(const u32*)(svb + (yy * 14 + xx) * 80 + dp * 4);
          r0[xx] = bflo(pr); r1[xx] = bfhi(pr);
        }
#pragma unroll
        for (int px = 0; px < 14; ++px) {
#pragma unroll
          for (int kx = 0; kx < 5; ++kx) {
            int xx = px + kx - 2;
            if (xx < 0 || xx > 13) continue;
            fm0[px] += w0[kx] * r0[xx];
            fm1[px] += w1[kx] * r1[xx];
          }
        }
      }
#pragma unroll
      for (int px = 0; px < 14; ++px)
        *(u32*)(sfmb + (py * 14 + px) * 80 + dp * 4) = cvt_pk_bf16(fm0[px], fm1[px]);
    }
  }
  __syncthreads();

  {
    const int dp = tid & 15, ng = tid >> 4;
    const int d0 = 2 * dp;
    float kv0[32], kv1[32], ks[32];
#pragma unroll
    for (int c = 0; c < 32; ++c) {
      const float* p = &skv[c * 36 + d0];
      kv0[c] = p[0]; kv1[c] = p[1];
    }
#pragma unroll
    for (int c = 0; c < 32; ++c) ks[c] = sksum[c];
#pragma unroll 2
    for (int i = 0; i < 13; ++i) {
      int n = i * 16 + ng;
      if (n < 196) {
        float o0 = 0.f, o1 = 0.f, pz = 0.f;
#pragma unroll
        for (int c4 = 0; c4 < 32; c4 += 4) {
          f4 qv = *(const f4*)(qp + n * 32 + c4);
#pragma unroll
          for (int j = 0; j < 4; ++j) {
            o0 += qv[j] * kv0[c4 + j];
            o1 += qv[j] * kv1[c4 + j];
            pz += qv[j] * ks[c4 + j];
          }
        }
        float z = 1.f / (pz + 1e-6f);
        u32 fmp = *(const u32*)(sfmb + n * 80 + dp * 4);
        f2 r; r[0] = fmaf(o0, z, bflo(fmp)); r[1] = fmaf(o1, z, bfhi(fmp));
        *(f2*)(yp + n * 32 + d0) = r;
      }
    }
  }
}

__global__ __launch_bounds__(256, 2) void proj_gemm_fb(
    const float* __restrict__ yv, const u16* __restrict__ wh, const u16* __restrict__ wl,
    const float* __restrict__ bias, float* __restrict__ out)
{
  __shared__ __align__(16) char lds[2][32768];
  const int tid  = threadIdx.x;
  const int lane = tid & 63, wv = tid >> 6;
  const int L  = ((int)blockIdx.x & 7) * 588 + ((int)blockIdx.x >> 3);
  const int rt = L / 3, ct = L - rt * 3;
  const int m0 = rt * 128, t0 = ct * 128;

  u32 a_rowb[4]; int a_d[4];
  {
    int sg = lane & 7, lr = lane >> 3;
#pragma unroll
    for (int j = 0; j < 4; ++j) {
      int r = (wv * 4 + j) * 8 + lr;
      int m = m0 + r;
      int b = m / 196, n = m - b * 196;
      a_rowb[j] = (u32)b * 75264u + (u32)n * 32u;
      a_d[j] = (sg ^ (r & 7)) * 4;
    }
  }
  const u16 *bh_src[2], *bl_src[2];
#pragma unroll
  for (int j = 0; j < 2; ++j) {
    int gi = (wv * 2 + j) * 64 + lane;
    int kb = gi >> 7, t = gi & 127;
    size_t o = (size_t)(t0 + t) * NC + kb * 8;
    bh_src[j] = wh + o;
    bl_src[j] = wl + o;
  }

  auto stage = [&](char* buf, int kh) {
#pragma unroll
    for (int j = 0; j < 4; ++j)
      gload_lds16(yv + a_rowb[j] + (size_t)kh * 6272 + a_d[j], buf + (wv * 4 + j) * 1024);
#pragma unroll
    for (int j = 0; j < 2; ++j) {
      gload_lds16(bh_src[j] + kh * 32, buf + 16384 + (wv * 2 + j) * 1024);
      gload_lds16(bl_src[j] + kh * 32, buf + 24576 + (wv * 2 + j) * 1024);
    }
  };

  const int wm = (wv & 1) * 64, wn = (wv >> 1) * 64;
  const int l15 = lane & 15, l4 = lane >> 4;
  int boff[4], aoff0[4], aoff1[4];
#pragma unroll
  for (int i = 0; i < 4; ++i) {
    boff[i] = (l4 * 128 + wn + i * 16 + l15) * 16;
    int r = wm + i * 16 + l15;
    aoff0[i] = r * 128 + (((l4 * 2)     ^ (r & 7)) * 16);
    aoff1[i] = r * 128 + (((l4 * 2 + 1) ^ (r & 7)) * 16);
  }

  f4 acc[4][4];
  const f4 fz = {0.f, 0.f, 0.f, 0.f};
#pragma unroll
  for (int i = 0; i < 4; ++i)
#pragma unroll
    for (int j = 0; j < 4; ++j) acc[i][j] = fz;

  stage(lds[0], 0);
  for (int kt = 0; kt < 12; ++kt) {
    __syncthreads();
    if (kt < 11) stage(lds[(kt + 1) & 1], kt + 1);
    char* buf = lds[kt & 1];
    bx8 bhf[4], blf[4];
#pragma unroll
    for (int i = 0; i < 4; ++i) {
      bhf[i] = *(const bx8*)(buf + 16384 + boff[i]);
      blf[i] = *(const bx8*)(buf + 24576 + boff[i]);
    }
#pragma unroll
    for (int mi = 0; mi < 4; ++mi) {
      f4 fa = *(const f4*)(buf + aoff0[mi]);
      f4 fb = *(const f4*)(buf + aoff1[mi]);
      bx8 ah, al;
#pragma unroll
      for (int e = 0; e < 4; ++e) { short h, l; split_hi_lo(fa[e], h, l); ah[e] = h; al[e] = l; }
#pragma unroll
      for (int e = 0; e < 4; ++e) { short h, l; split_hi_lo(fb[e], h, l); ah[4+e] = h; al[4+e] = l; }
#pragma unroll
      for (int ni = 0; ni < 4; ++ni) {
        acc[mi][ni] = __builtin_amdgcn_mfma_f32_16x16x32_bf16(ah, bhf[ni], acc[mi][ni], 0, 0, 0);
        acc[mi][ni] = __builtin_amdgcn_mfma_f32_16x16x32_bf16(ah, blf[ni], acc[mi][ni], 0, 0, 0);
        acc[mi][ni] = __builtin_amdgcn_mfma_f32_16x16x32_bf16(al, bhf[ni], acc[mi][ni], 0, 0, 0);
      }
    }
  }

  float biasv[4];
#pragma unroll
  for (int ni = 0; ni < 4; ++ni) biasv[ni] = bias[t0 + wn + ni * 16 + l15];
#pragma unroll
  for (int mi = 0; mi < 4; ++mi) {
#pragma unroll
    for (int rr = 0; rr < 4; ++rr) {
      int m = m0 + wm + mi * 16 + l4 * 4 + rr;
      size_t ob = (size_t)m * 384 + t0 + wn;
#pragma unroll
      for (int ni = 0; ni < 4; ++ni)
        out[ob + ni * 16 + l15] = acc[mi][ni][rr] + biasv[ni];
    }
  }
}

// ---------------- launcher ----------------
extern "C" void kernel_launch(void* const* d_in, const int* in_sizes, int n_in,
                              void* d_out, int out_size, void* d_ws, size_t ws_size,
                              hipStream_t stream)
{
  const float* x      = (const float*)d_in[0];
  const float* qkv_w  = (const float*)d_in[1];
  const float* qkv_b  = (const float*)d_in[2];
  const float* proj_w = (const float*)d_in[3];
  const float* proj_b = (const float*)d_in[4];
  const float* dwc_w  = (const float*)d_in[5];
  const float* dwc_b  = (const float*)d_in[6];
  const float* pos    = (const float*)d_in[7];
  float* out = (float*)d_out;
  char* ws = (char*)d_ws;

  if (ws_size >= NEED_MAIN) {
    float* qb  = (float*)(ws + OFF_Q);
    float* kb  = (float*)(ws + OFF_K);
    u16*   vb  = (u16*)(ws + OFF_V);
    u16*   wqh = (u16*)(ws + OFF_WQH);
    u16*   wql = (u16*)(ws + OFF_WQL);
    u16*   wph = (u16*)(ws + OFF_WPH);
    u16*   wpl = (u16*)(ws + OFF_WPL);
    u16*   xh  = (u16*)(ws + OFF_XH);
    u16*   xl  = (u16*)(ws + OFF_XL);
    u16*   yh  = (u16*)(ws + OFF_K);   // overlays k (safe: k consumed in-phase)
    u16*   yl  = (u16*)(ws + OFF_V);   // overlays v (safe: v consumed in-phase)

    split_weights<<<1728, 256, 0, stream>>>(qkv_w, proj_w, wqh, wql, wph, wpl);
    split_x<<<37632, 256, 0, stream>>>(x, xh, xl);
    qkv_gemm<<<14112, 256, 0, stream>>>(xh, xl, wqh, wql, qkv_b, pos, qb, kb, vb);
    attn_conv<<<12288, 256, 0, stream>>>(qb, kb, vb, yh, yl, dwc_w, dwc_b);
    proj_gemm<<<4704, 256, 0, stream>>>(yh, yl, wph, wpl, proj_b, out);
  } else {
    float* qb  = (float*)(ws + OFF_Q_FB);
    float* kb  = (float*)(ws + OFF_K_FB);
    float* vb  = (float*)(ws + OFF_V_FB);
    u16*   wqh = (u16*)(ws + OFF_WQH_FB);
    u16*   wql = (u16*)(ws + OFF_WQL_FB);
    u16*   wph = (u16*)(ws + OFF_WPH_FB);
    u16*   wpl = (u16*)(ws + OFF_WPL_FB);

    split_weights<<<1728, 256, 0, stream>>>(qkv_w, proj_w, wqh, wql, wph, wpl);
    qkv_gemm_fb<<<14112, 256, 0, stream>>>(x, wqh, wql, qkv_b, pos, qb, kb, vb);
    attn_conv_fb<<<12288, 256, 0, stream>>>(qb, kb, vb, vb, dwc_w, dwc_b);
    proj_gemm_fb<<<4704, 256, 0, stream>>>(vb, wph, wpl, proj_b, out);
  }
}